// Round 5
// baseline (18358.699 us; speedup 1.0000x reference)
//
#include <hip/hip_runtime.h>
#include <hip/hip_bf16.h>

#define N_ROWS 32768
#define K_CODES 4096
#define D_DIM 256
#define CAP 128
#define MARGIN_T 1e-3f
#define RB 8
#define SLOTS 8

// ---- d_ws layout (bytes) -- total 4,882,432 ----
#define WS_COUNTS    0          // float[4096]
#define WS_LOSSP     16384      // float[32768]
#define WS_IDX       147456     // int[32768]
#define WS_Z2        278528     // float[32768]
#define WS_E2        409600     // float[4096]
#define WS_RMAX      425984     // (unused, layout stability)
#define WS_CNT       557056     // (unused, layout stability)
#define WS_DW        688128     // float[1048576] -> ends 4882432

// ---- d_out scratch (all regions rewritten by k3/k5 after consumption) ----
#define DO_ZB        0          // ushort[32768*256] = 16 MB (panel layout)
#define DO_WB        16777216   // ushort[4096*256]  =  2 MB (panel layout)
#define DO_CAND      18874368   // uint[32768][16][8] = 16 MB -> ends 35651584
#define DO_CNT8      35651584   // uchar[32768][16]  = 512 KB -> ends 36163584

typedef __attribute__((ext_vector_type(8)))  short bf16x8;
typedef __attribute__((ext_vector_type(16))) float f32x16;
typedef __attribute__((ext_vector_type(8)))  unsigned short us8;

// ---------------------------------------------------------------------------
// K1: z2/e2 with numpy's exact pairwise structure (proven in R1)
// ---------------------------------------------------------------------------
__global__ void k1_norms(const float* __restrict__ z, const float* __restrict__ w,
                         float* __restrict__ z2, float* __restrict__ e2)
{
#pragma clang fp contract(off)
    int gid = blockIdx.x * blockDim.x + threadIdx.x;
    const float* row;
    float* outp;
    if (gid < N_ROWS) { row = z + (size_t)gid * D_DIM; outp = z2 + gid; }
    else if (gid < N_ROWS + K_CODES) { row = w + (size_t)(gid - N_ROWS) * D_DIM; outp = e2 + (gid - N_ROWS); }
    else return;

    float total = 0.0f;
    for (int half = 0; half < 2; half++) {
        const float* x = row + half * 128;
        float r[8];
#pragma unroll
        for (int j = 0; j < 8; j++) { float v = x[j]; r[j] = v * v; }
        for (int i = 8; i < 128; i += 8) {
#pragma unroll
            for (int j = 0; j < 8; j++) { float v = x[i + j]; r[j] += v * v; }
        }
        float s = ((r[0] + r[1]) + (r[2] + r[3])) + ((r[4] + r[5]) + (r[6] + r[7]));
        if (half == 0) total = s; else total = total + s;
    }
    *outp = total;
}

// ---------------------------------------------------------------------------
// KCONV v2 (proven R4): fp32 -> bf16 (RNE) in "LDS-image" PANEL layout so
// k2's staging is a straight contiguous copy. Panel: for each 256-row block
// B and BK=32 window kk, 16 KB at ((B*8)+kk)*16384. Byte offset inside:
// ((g*2+s)*64 + lane)*16 holds row (B*256 + g*32 + (lane&31)),
// cols (kk*32 + s*16 + (lane>>5)*8 ..+8). Bit-identical LDS bytes vs R3.
// ---------------------------------------------------------------------------
__device__ inline unsigned short f2b(float f) {
    __hip_bfloat16 h = __float2bfloat16(f);
    return *(unsigned short*)&h;
}

__global__ void kconv(const float* __restrict__ z, const float* __restrict__ w,
                      unsigned short* __restrict__ zb, unsigned short* __restrict__ wb)
{
    const int lane  = threadIdx.x & 63;
    const int gwave = blockIdx.x * 4 + (threadIdx.x >> 6);   // 0..4607
    const int kk    = gwave & 7;
    const int row   = (gwave >> 3) * 64 + lane;              // 0..36863
    const float* src;
    unsigned short* panel;
    int g;
    if (row < N_ROWS) {
        src   = z + (size_t)row * D_DIM;
        panel = zb + ((size_t)((row >> 8) * 8 + kk) << 13);
        g     = (row >> 5) & 7;
    } else {
        int c = row - N_ROWS;
        src   = w + (size_t)c * D_DIM;
        panel = wb + ((size_t)((c >> 8) * 8 + kk) << 13);
        g     = (c >> 5) & 7;
    }
    const int r31 = row & 31;
    const float* s0 = src + kk * 32;
#pragma unroll
    for (int s = 0; s < 2; s++)
#pragma unroll
        for (int h = 0; h < 2; h++) {
            float4 a = *(const float4*)(s0 + s * 16 + h * 8);
            float4 b = *(const float4*)(s0 + s * 16 + h * 8 + 4);
            us8 o;
            o[0] = f2b(a.x); o[1] = f2b(a.y); o[2] = f2b(a.z); o[3] = f2b(a.w);
            o[4] = f2b(b.x); o[5] = f2b(b.y); o[6] = f2b(b.z); o[7] = f2b(b.w);
            *(us8*)(panel + (((g * 2 + s) * 64 + h * 32 + r31) << 3)) = o;
        }
}

// ---------------------------------------------------------------------------
// async global->LDS, 16B per lane. LDS dest = wave-uniform base + lane*16.
// ---------------------------------------------------------------------------
__device__ inline void gload16(const void* g, void* l)
{
    __builtin_amdgcn_global_load_lds(
        (const __attribute__((address_space(1))) unsigned int*)g,
        (__attribute__((address_space(3))) unsigned int*)l,
        16, 0, 0);
}

// ---------------------------------------------------------------------------
// K2 v5: 256x256-tile bf16 MFMA GEMM t = W @ Z^T (structure proven R4:
// 512 thr = 8 waves 2x4, wave tile 128x64 = acc[4][2], BK=32 dbuf LDS,
// contiguous panel staging, XCD-bijective swizzle).
//
// NEW: the candidate append path has ZERO global atomics. R2-R4 post-mortem:
// ~1.5M device-scope atomicAdd(&cnt[n]) + dependent scattered 4B stores was
// the latency wall (~10^5 cyc/block epilogue; WRITE_SIZE 51-56 MB of
// partial-line writebacks; MfmaUtil pinned at 7-8%). Now: per-(row,block)
// fixed 8-slot region cand2[n][cb][8] + count byte cnt8[n][cb]; slots
// reserved via LDS atomics; global writes are plain stores to block-private
// regions (all 16 cb-blocks of a row-tile on one XCD by swizzle).
// Overflow (>8 hits) -> cnt8=255 -> rescore full-scan fallback (exact).
//
// Threshold semantics unchanged (block-local 256-code row max - MARGIN):
// superset of the proven global-threshold set; packed (key|code) entries
// let k_rescore recover the global bf16 max and re-filter exactly.
// ---------------------------------------------------------------------------
__global__ __launch_bounds__(512, 2) void k2_scan(
    const unsigned short* __restrict__ zb, const unsigned short* __restrict__ wb,
    unsigned char* __restrict__ cnt8, unsigned int* __restrict__ cand2)
{
    __shared__ char smem[65536];
    const int tid  = threadIdx.x;
    const int lane = tid & 63;
    const int wid  = tid >> 6;     // 0..7
    const int wm   = wid >> 2;     // code-wave 0..1
    const int wn   = wid & 3;      // row-wave 0..3
    const int m    = lane & 31;
    const int half = lane >> 5;

    // bijective XCD swizzle: XCD(r_hw) == o/256 (proven R3/R4: FETCH 17MB)
    const int r_hw = blockIdx.y * 16 + blockIdx.x;
    const int o    = (r_hw & 7) * 256 + (r_hw >> 3);
    const int cb   = o & 15;       // code-block 0..15
    const int rb   = o >> 4;       // row-block  0..127
    const int rowBase  = rb * 256;
    const int codeBase = cb * 256;

    // linear panel copy: A panel (wb) and B panel (zb) for window kk.
    auto stage = [&](int kk, int buf) {
        char* Ab = smem + buf * 32768;
        char* Bb = Ab + 16384;
        const unsigned short* Ap = wb + ((size_t)(cb * 8 + kk) << 13);
        const unsigned short* Bp = zb + ((size_t)(rb * 8 + kk) << 13);
#pragma unroll
        for (int i = 0; i < 2; i++) {
            gload16(Ap + (size_t)((i * 512 + tid) << 3), Ab + (size_t)(i * 512 + tid) * 16);
            gload16(Bp + (size_t)((i * 512 + tid) << 3), Bb + (size_t)(i * 512 + tid) * 16);
        }
    };

    f32x16 acc[4][2];
    {
        f32x16 zz = {};
#pragma unroll
        for (int ms = 0; ms < 4; ms++)
#pragma unroll
            for (int ns = 0; ns < 2; ns++) acc[ms][ns] = zz;
    }

    stage(0, 0);

    for (int kk = 0; kk < 8; kk++) {
        const int buf = kk & 1;
        __syncthreads();                       // drains vmcnt -> buf ready
        if (kk + 1 < 8) stage(kk + 1, buf ^ 1);
        const char* Ab = smem + buf * 32768;
        const char* Bb = Ab + 16384;
#pragma unroll
        for (int s = 0; s < 2; s++) {
            bf16x8 af[4], bfr[2];
#pragma unroll
            for (int ms = 0; ms < 4; ms++)
                af[ms] = *(const bf16x8*)(Ab + (size_t)(((wm * 4 + ms) * 2 + s) * 64 + lane) * 16);
#pragma unroll
            for (int ns = 0; ns < 2; ns++)
                bfr[ns] = *(const bf16x8*)(Bb + (size_t)(((wn * 2 + ns) * 2 + s) * 64 + lane) * 16);
#pragma unroll
            for (int ms = 0; ms < 4; ms++)
#pragma unroll
                for (int ns = 0; ns < 2; ns++)
                    acc[ms][ns] = __builtin_amdgcn_mfma_f32_32x32x16_bf16(
                        af[ms], bfr[ns], acc[ms][ns], 0, 0, 0);
        }
    }

    // ---- epilogue: block-local per-row max over all 256 codes ----
    float tmax[2] = {-1e30f, -1e30f};
#pragma unroll
    for (int ms = 0; ms < 4; ms++)
#pragma unroll
        for (int ns = 0; ns < 2; ns++)
#pragma unroll
            for (int r = 0; r < 16; r++)
                tmax[ns] = fmaxf(tmax[ns], acc[ms][ns][r]);
#pragma unroll
    for (int ns = 0; ns < 2; ns++)
        tmax[ns] = fmaxf(tmax[ns], __shfl_xor(tmax[ns], 32));

    __syncthreads();                 // GEMM LDS dead; reuse for rowmax + lcnt
    float* rmx  = (float*)smem;      // [2][256]: [wm][local row]
    int*   lcnt = (int*)(smem + 2048);   // [256] per-row slot counters
    if (lane < 32) {
        rmx[wm * 256 + wn * 64 + 0 * 32 + lane] = tmax[0];
        rmx[wm * 256 + wn * 64 + 1 * 32 + lane] = tmax[1];
    }
    if (tid < 256) lcnt[tid] = 0;
    __syncthreads();

    float thr[2];
#pragma unroll
    for (int ns = 0; ns < 2; ns++) {
        const int lr = wn * 64 + ns * 32 + m;
        thr[ns] = fmaxf(rmx[lr], rmx[256 + lr]) - MARGIN_T;
    }

    // ---- append keepers: LDS-atomic slot reservation + plain stores ----
#pragma unroll
    for (int ms = 0; ms < 4; ms++)
#pragma unroll
        for (int ns = 0; ns < 2; ns++)
#pragma unroll
            for (int r = 0; r < 16; r++) {
                float v = acc[ms][ns][r];
                if (v >= thr[ns]) {
                    const int lr = wn * 64 + ns * 32 + m;
                    int slot = atomicAdd(&lcnt[lr], 1);        // LDS atomic
                    if (slot < SLOTS) {
                        int code = codeBase + wm * 128 + ms * 32
                                 + ((r & 3) + 8 * (r >> 2) + 4 * half);
                        int b = __float_as_int(v);
                        unsigned key = (unsigned)b ^ ((unsigned)(b >> 31) | 0x80000000u);
                        unsigned entry = (key & 0xFFFFF000u) | (unsigned)code;
                        cand2[((size_t)(rowBase + lr) * 16 + cb) * SLOTS + slot] = entry;
                    }
                }
            }

    __syncthreads();
    if (tid < 256) {
        int cf = lcnt[tid];
        cnt8[(size_t)(rowBase + tid) * 16 + cb] =
            (cf > SLOTS) ? (unsigned char)255 : (unsigned char)cf;
    }
}

// ---------------------------------------------------------------------------
// K_RESCORE v6: one WAVE per row.
// Gather: lanes 0..15 read cnt8[n][cb] (one 16B line) + their <=8 packed
//   entries (row's 512B cand2 slice), prefix-scan compact into LDS sbuf.
//   Any cnt8==255 -> full-scan fallback (exact).
// Filter (proven v5 logic): wave-max of packed keys == global bf16 row max
//   (lower-bounded within 1.5e-5 by 20-bit truncation); keep entries with
//   score >= gm - MARGIN - 5e-5 (superset of proven two-pass set).
// Phase B: exact fp32 rescore of survivors (serial 256-FMA chain, ascending
//   d, single accumulator = bit-identical to BLAS sgemm), (d,k) tie-break.
// ---------------------------------------------------------------------------
__global__ __launch_bounds__(64) void k_rescore(
    const float* __restrict__ z, const float* __restrict__ w,
    const float* __restrict__ z2, const float* __restrict__ e2,
    const unsigned char* __restrict__ cnt8, const unsigned int* __restrict__ cand2,
    int* __restrict__ idx_out)
{
#pragma clang fp contract(off)
    const int lane = threadIdx.x;
    const int n    = blockIdx.x;

    __shared__ float4   wst[RB * 65];   // 8320 B
    __shared__ float4   zst[64];        // 1 KB
    __shared__ unsigned sbuf[CAP];      // gathered packed entries
    __shared__ int      surv[CAP];      // filtered survivor codes

    zst[lane] = ((const float4*)(z + (size_t)n * D_DIM))[lane];

    // ---- gather ----
    int c = 0;
    if (lane < 16) c = cnt8[(size_t)n * 16 + lane];
    const bool ovf = __any(c == 255);
    int total = 0;
    if (!ovf) {
        int inc = c;
#pragma unroll
        for (int d = 1; d < 16; d <<= 1) {
            int t = __shfl_up(inc, d);
            if (lane >= d) inc += t;    // lanes >=16 irrelevant
        }
        int excl = inc - c;
        if (lane < 16 && c > 0) {
            const unsigned* rp = cand2 + (size_t)n * 128 + lane * SLOTS;
            for (int j = 0; j < c; j++) sbuf[excl + j] = rp[j];
        }
        total = __shfl(inc, 15);        // <= 16*8 = 128
    }
    __syncthreads();

    // ---- filter ----
    const bool fallback = ovf || (total <= 0) || (total > CAP);
    int nt;
    if (!fallback) {
        unsigned e0 = (lane < total)      ? sbuf[lane]      : 0u;
        unsigned e1 = (lane + 64 < total) ? sbuf[lane + 64] : 0u;
        unsigned k0 = e0 & 0xFFFFF000u, k1 = e1 & 0xFFFFF000u;
        unsigned km = k0 > k1 ? k0 : k1;
#pragma unroll
        for (int off = 32; off > 0; off >>= 1) {
            unsigned t = __shfl_xor(km, off);
            km = t > km ? t : km;
        }
        int bm = (km & 0x80000000u) ? (int)(km ^ 0x80000000u) : (int)~km;
        const float thr = __int_as_float(bm) - MARGIN_T - 5e-5f;

        int tot = 0;
        for (int base = 0; base < total; base += 64) {
            unsigned e = (base == 0) ? e0 : e1;
            bool keep = false;
            if (base + lane < total) {
                unsigned ky = e & 0xFFFFF000u;
                int b = (ky & 0x80000000u) ? (int)(ky ^ 0x80000000u) : (int)~ky;
                keep = (__int_as_float(b) >= thr);
            }
            unsigned long long bal = __ballot(keep);
            int pos = tot + (int)__popcll(bal & ((1ull << lane) - 1ull));
            if (keep) surv[pos] = (int)(e & 0xFFFu);
            tot += (int)__popcll(bal);
        }
        nt = tot;            // >= 1 (max-key entry always passes)
    } else {
        nt = K_CODES;
    }
    __syncthreads();

    // ---- phase B: exact rescore ----
    float bd = __builtin_inff(); int bk = K_CODES;
    const float z2v = z2[n];

    float4 regs[RB];
    auto load_regs = [&](int base) {
#pragma unroll
        for (int j = 0; j < RB; j++) {
            int s = base + j;
            int k = 0;
            if (s < nt) k = fallback ? s : surv[s];
            if ((unsigned)k >= (unsigned)K_CODES) k = 0;   // defensive
            regs[j] = ((const float4*)(w + (size_t)k * D_DIM))[lane];
        }
    };

    load_regs(0);
    for (int base = 0; base < nt; base += RB) {
        int nb = nt - base; if (nb > RB) nb = RB;
#pragma unroll
        for (int j = 0; j < RB; j++) wst[j * 65 + lane] = regs[j];
        if (base + RB < nt) load_regs(base + RB);   // prefetch during chain
        __syncthreads();
        if (lane < nb) {
            int k = fallback ? (base + lane) : surv[base + lane];
            if ((unsigned)k >= (unsigned)K_CODES) k = 0;   // defensive
            const float4* wp = &wst[lane * 65];
            float tacc = 0.0f;
#pragma unroll
            for (int d4 = 0; d4 < 64; d4++) {
                float4 wv = wp[d4];
                float4 zv = zst[d4];
                tacc = __builtin_fmaf(zv.x, wv.x, tacc);
                tacc = __builtin_fmaf(zv.y, wv.y, tacc);
                tacc = __builtin_fmaf(zv.z, wv.z, tacc);
                tacc = __builtin_fmaf(zv.w, wv.w, tacc);
            }
            float u  = z2v - 2.0f * tacc;   // 2*tacc exact -> single rounding
            float dv = u + e2[k];
            if (dv < bd || (dv == bd && k < bk)) { bd = dv; bk = k; }
        }
        __syncthreads();
    }

#pragma unroll
    for (int off = 1; off < 64; off <<= 1) {
        float od = __shfl_xor(bd, off);
        int   ok = __shfl_xor(bk, off);
        if (od < bd || (od == bd && ok < bk)) { bd = od; bk = ok; }
    }
    if (lane == 0) idx_out[n] = bk;
}

// ---------------------------------------------------------------------------
// K3: gather z_q, STE output, loss partials, counts + dw atomics.
// ---------------------------------------------------------------------------
__global__ void k3_scatter(const float* __restrict__ z, const float* __restrict__ w,
                           const int* __restrict__ idx_in,
                           float* __restrict__ counts, float* __restrict__ lossp,
                           float* __restrict__ dw, float* __restrict__ out_zq,
                           float* __restrict__ out_idx)
{
#pragma clang fp contract(off)
    const int n = blockIdx.x;
    const int t = threadIdx.x;
    int idx = idx_in[n];
    if (idx < 0) idx = 0;
    if (idx >= K_CODES) idx = K_CODES - 1;     // defensive clamp (no fault)
    if (t == 0) {
        out_idx[n] = (float)idx;
        atomicAdd(&counts[idx], 1.0f);
    }
    float zv = z[(size_t)n * D_DIM + t];
    float wq = w[(size_t)idx * D_DIM + t];
    out_zq[(size_t)n * D_DIM + t] = zv + (wq - zv);
    float df = zv - wq;
    float sq = df * df;
    atomicAdd(&dw[(size_t)idx * D_DIM + t], zv);

    __shared__ float red[256];
    red[t] = sq; __syncthreads();
    for (int s = 128; s > 0; s >>= 1) {
        if (t < s) red[t] += red[t + s];
        __syncthreads();
    }
    if (t == 0) lossp[n] = red[0];
}

// ---------------------------------------------------------------------------
// K4: vq_loss finalize + new_cs (Laplace smoothing). Single block, 1024 thr.
// ---------------------------------------------------------------------------
__global__ void k4_cs(const float* __restrict__ lossp, const float* __restrict__ counts,
                      const float* __restrict__ cs_in, float* __restrict__ out_loss,
                      float* __restrict__ out_cs)
{
#pragma clang fp contract(off)
    const int t = threadIdx.x;
    __shared__ float red[1024];
    __shared__ float pre[K_CODES];

    float s = 0.0f;
    for (int i = t; i < N_ROWS; i += 1024) s += lossp[i];
    red[t] = s; __syncthreads();
    for (int st = 512; st > 0; st >>= 1) {
        if (t < st) red[t] += red[t + st];
        __syncthreads();
    }
    if (t == 0) out_loss[0] = 0.25f * (red[0] / 8388608.0f);
    __syncthreads();

    const float DEC = 0.99f;
    const float OMD = (float)(1.0 - 0.99);
    float mine[4];
#pragma unroll
    for (int q = 0; q < 4; q++) {
        int k = t + q * 1024;
        float t1 = DEC * cs_in[k];
        float t2 = OMD * counts[k];
        float p = t1 + t2;
        pre[k] = p; mine[q] = p;
    }
    float psum = (mine[0] + mine[1]) + (mine[2] + mine[3]);
    red[t] = psum; __syncthreads();
    for (int st = 512; st > 0; st >>= 1) {
        if (t < st) red[t] += red[t + st];
        __syncthreads();
    }
    float nsum = red[0];
    const float KEPS = (float)(4096.0 * 1e-5);
    float denom = nsum + KEPS;
#pragma unroll
    for (int q = 0; q < 4; q++) {
        int k = t + q * 1024;
        float v = ((pre[k] + 1e-5f) / denom) * nsum;
        out_cs[k] = v;
    }
}

// ---------------------------------------------------------------------------
// K5: new_ema_w = 0.99*ema_w + 0.01*dw ; new_weight = new_ema_w / new_cs[k]
// ---------------------------------------------------------------------------
__global__ void k5_emaw(const float* __restrict__ ema_w, const float* __restrict__ dw,
                        const float* __restrict__ newcs, float* __restrict__ out_w,
                        float* __restrict__ out_emaw)
{
#pragma clang fp contract(off)
    const int i = blockIdx.x * 256 + threadIdx.x;
    const int k = i >> 8;
    const float OMD = (float)(1.0 - 0.99);
    float t1 = 0.99f * ema_w[i];
    float t2 = OMD * dw[i];
    float ne = t1 + t2;
    out_emaw[i] = ne;
    out_w[i] = ne / newcs[k];
}

extern "C" void kernel_launch(void* const* d_in, const int* in_sizes, int n_in,
                              void* d_out, int out_size, void* d_ws, size_t ws_size,
                              hipStream_t stream)
{
    const float* z    = (const float*)d_in[0];
    const float* w    = (const float*)d_in[1];
    const float* cs   = (const float*)d_in[2];
    const float* emaw = (const float*)d_in[3];

    float* out      = (float*)d_out;
    float* out_zq   = out;                    // 8388608
    float* out_idx  = out + 8388608;          // 32768
    float* out_loss = out + 8421376;          // 1
    float* out_w    = out + 8421377;          // 1048576
    float* out_cs   = out + 9469953;          // 4096
    float* out_emaw = out + 9474049;          // 1048576

    char* ws = (char*)d_ws;
    float*          counts  = (float*)(ws + WS_COUNTS);
    float*          lossp   = (float*)(ws + WS_LOSSP);
    int*            idx_int = (int*)  (ws + WS_IDX);
    float*          z2      = (float*)(ws + WS_Z2);
    float*          e2      = (float*)(ws + WS_E2);
    float*          dw      = (float*)(ws + WS_DW);

    // big scratch lives in d_out (consumed by rescore before k3/k5 rewrite it)
    char* ob = (char*)d_out;
    unsigned short* zb    = (unsigned short*)(ob + DO_ZB);
    unsigned short* wb    = (unsigned short*)(ob + DO_WB);
    unsigned int*   cand2 = (unsigned int*)  (ob + DO_CAND);
    unsigned char*  cnt8  = (unsigned char*) (ob + DO_CNT8);

    hipMemsetAsync(counts, 0, K_CODES * sizeof(float), stream);
    hipMemsetAsync(dw, 0, (size_t)K_CODES * D_DIM * sizeof(float), stream);

    k1_norms<<<(N_ROWS + K_CODES) / 256, 256, 0, stream>>>(z, w, z2, e2);

    // 4608 waves: (36864 rows / 64 rows-per-wave) * 8 kk-panels; 4 waves/block
    kconv<<<1152, 256, 0, stream>>>(z, w, zb, wb);

    dim3 g2(16, 128);   // x = code-block, y = row-block (swizzled in-kernel)
    k2_scan<<<g2, 512, 0, stream>>>(zb, wb, cnt8, cand2);

    k_rescore<<<N_ROWS, 64, 0, stream>>>(z, w, z2, e2, cnt8, cand2, idx_int);

    k3_scatter<<<N_ROWS, 256, 0, stream>>>(z, w, idx_int, counts, lossp,
                                           dw, out_zq, out_idx);

    k4_cs<<<1, 1024, 0, stream>>>(lossp, counts, cs, out_loss, out_cs);

    k5_emaw<<<K_CODES, 256, 0, stream>>>(emaw, dw, out_cs, out_w, out_emaw);
}

// Round 6
// 1387.657 us; speedup vs baseline: 13.2300x; 13.2300x over previous
//
#include <hip/hip_runtime.h>
#include <hip/hip_bf16.h>

#define N_ROWS 32768
#define K_CODES 4096
#define D_DIM 256
#define CAP 128
#define MARGIN_T 1e-3f
#define RB 8
#define SLOTS 8

// ---- d_ws layout (bytes) -- total 4,882,432 ----
#define WS_COUNTS    0          // float[4096]
#define WS_LOSSP     16384      // float[32768]
#define WS_IDX       147456     // int[32768]
#define WS_Z2        278528     // float[32768]
#define WS_E2        409600     // float[4096]
#define WS_DW        688128     // float[1048576] -> ends 4882432

// ---- d_out scratch (all regions consumed by rescore before k3/k4/k5 rewrite) ----
#define DO_ZB        0          // ushort[32768*256] = 16 MB (panel layout)
#define DO_WB        16777216   // ushort[4096*256]  =  2 MB (panel layout)
#define DO_CAND      18874368   // uint[32768][16][8] = 16 MB -> ends 35651584
#define DO_CNT8      35651584   // uchar[32768][16]  = 512 KB -> ends 36175872
#define DO_LMAX      36175872   // float[32768][16]  =   2 MB -> ends 38273024 (< 42.09 MB)

typedef __attribute__((ext_vector_type(8)))  short bf16x8;
typedef __attribute__((ext_vector_type(16))) float f32x16;
typedef __attribute__((ext_vector_type(8)))  unsigned short us8;

// ---------------------------------------------------------------------------
// K1: z2/e2 with numpy's exact pairwise structure (proven in R1)
// ---------------------------------------------------------------------------
__global__ void k1_norms(const float* __restrict__ z, const float* __restrict__ w,
                         float* __restrict__ z2, float* __restrict__ e2)
{
#pragma clang fp contract(off)
    int gid = blockIdx.x * blockDim.x + threadIdx.x;
    const float* row;
    float* outp;
    if (gid < N_ROWS) { row = z + (size_t)gid * D_DIM; outp = z2 + gid; }
    else if (gid < N_ROWS + K_CODES) { row = w + (size_t)(gid - N_ROWS) * D_DIM; outp = e2 + (gid - N_ROWS); }
    else return;

    float total = 0.0f;
    for (int half = 0; half < 2; half++) {
        const float* x = row + half * 128;
        float r[8];
#pragma unroll
        for (int j = 0; j < 8; j++) { float v = x[j]; r[j] = v * v; }
        for (int i = 8; i < 128; i += 8) {
#pragma unroll
            for (int j = 0; j < 8; j++) { float v = x[i + j]; r[j] += v * v; }
        }
        float s = ((r[0] + r[1]) + (r[2] + r[3])) + ((r[4] + r[5]) + (r[6] + r[7]));
        if (half == 0) total = s; else total = total + s;
    }
    *outp = total;
}

// ---------------------------------------------------------------------------
// KCONV v2 (proven R4): fp32 -> bf16 (RNE) in "LDS-image" PANEL layout so
// k2's staging is a straight contiguous copy. Bit-identical LDS bytes vs R3.
// ---------------------------------------------------------------------------
__device__ inline unsigned short f2b(float f) {
    __hip_bfloat16 h = __float2bfloat16(f);
    return *(unsigned short*)&h;
}

__global__ void kconv(const float* __restrict__ z, const float* __restrict__ w,
                      unsigned short* __restrict__ zb, unsigned short* __restrict__ wb)
{
    const int lane  = threadIdx.x & 63;
    const int gwave = blockIdx.x * 4 + (threadIdx.x >> 6);   // 0..4607
    const int kk    = gwave & 7;
    const int row   = (gwave >> 3) * 64 + lane;              // 0..36863
    const float* src;
    unsigned short* panel;
    int g;
    if (row < N_ROWS) {
        src   = z + (size_t)row * D_DIM;
        panel = zb + ((size_t)((row >> 8) * 8 + kk) << 13);
        g     = (row >> 5) & 7;
    } else {
        int c = row - N_ROWS;
        src   = w + (size_t)c * D_DIM;
        panel = wb + ((size_t)((c >> 8) * 8 + kk) << 13);
        g     = (c >> 5) & 7;
    }
    const int r31 = row & 31;
    const float* s0 = src + kk * 32;
#pragma unroll
    for (int s = 0; s < 2; s++)
#pragma unroll
        for (int h = 0; h < 2; h++) {
            float4 a = *(const float4*)(s0 + s * 16 + h * 8);
            float4 b = *(const float4*)(s0 + s * 16 + h * 8 + 4);
            us8 o;
            o[0] = f2b(a.x); o[1] = f2b(a.y); o[2] = f2b(a.z); o[3] = f2b(a.w);
            o[4] = f2b(b.x); o[5] = f2b(b.y); o[6] = f2b(b.z); o[7] = f2b(b.w);
            *(us8*)(panel + (((g * 2 + s) * 64 + h * 32 + r31) << 3)) = o;
        }
}

// ---------------------------------------------------------------------------
// async global->LDS, 16B per lane. LDS dest = wave-uniform base + lane*16.
// ---------------------------------------------------------------------------
__device__ inline void gload16(const void* g, void* l)
{
    __builtin_amdgcn_global_load_lds(
        (const __attribute__((address_space(1))) unsigned int*)g,
        (__attribute__((address_space(3))) unsigned int*)l,
        16, 0, 0);
}

// ---------------------------------------------------------------------------
// K2 v5.1: identical GEMM + atomic-free append structure to R5 (512 thr =
// 8 waves 2x4, wave tile 128x64 = acc[4][2], BK=32 dbuf LDS, panel staging,
// XCD-bijective swizzle, LDS-atomic slot reservation into per-(row,block)
// 8-slot regions). ONE addition: store the exact fp32 block-local row max
// to lmax[n][cb] so rescore can reconstruct the exact global row max and
// prune overflowed blocks whose max is below the global threshold.
// ---------------------------------------------------------------------------
__global__ __launch_bounds__(512, 2) void k2_scan(
    const unsigned short* __restrict__ zb, const unsigned short* __restrict__ wb,
    unsigned char* __restrict__ cnt8, unsigned int* __restrict__ cand2,
    float* __restrict__ lmax)
{
    __shared__ char smem[65536];
    const int tid  = threadIdx.x;
    const int lane = tid & 63;
    const int wid  = tid >> 6;     // 0..7
    const int wm   = wid >> 2;     // code-wave 0..1
    const int wn   = wid & 3;      // row-wave 0..3
    const int m    = lane & 31;
    const int half = lane >> 5;

    // bijective XCD swizzle: XCD(r_hw) == o/256 (proven R3/R4: FETCH 17MB)
    const int r_hw = blockIdx.y * 16 + blockIdx.x;
    const int o    = (r_hw & 7) * 256 + (r_hw >> 3);
    const int cb   = o & 15;       // code-block 0..15
    const int rb   = o >> 4;       // row-block  0..127
    const int rowBase  = rb * 256;
    const int codeBase = cb * 256;

    // linear panel copy: A panel (wb) and B panel (zb) for window kk.
    auto stage = [&](int kk, int buf) {
        char* Ab = smem + buf * 32768;
        char* Bb = Ab + 16384;
        const unsigned short* Ap = wb + ((size_t)(cb * 8 + kk) << 13);
        const unsigned short* Bp = zb + ((size_t)(rb * 8 + kk) << 13);
#pragma unroll
        for (int i = 0; i < 2; i++) {
            gload16(Ap + (size_t)((i * 512 + tid) << 3), Ab + (size_t)(i * 512 + tid) * 16);
            gload16(Bp + (size_t)((i * 512 + tid) << 3), Bb + (size_t)(i * 512 + tid) * 16);
        }
    };

    f32x16 acc[4][2];
    {
        f32x16 zz = {};
#pragma unroll
        for (int ms = 0; ms < 4; ms++)
#pragma unroll
            for (int ns = 0; ns < 2; ns++) acc[ms][ns] = zz;
    }

    stage(0, 0);

    for (int kk = 0; kk < 8; kk++) {
        const int buf = kk & 1;
        __syncthreads();                       // drains vmcnt -> buf ready
        if (kk + 1 < 8) stage(kk + 1, buf ^ 1);
        const char* Ab = smem + buf * 32768;
        const char* Bb = Ab + 16384;
#pragma unroll
        for (int s = 0; s < 2; s++) {
            bf16x8 af[4], bfr[2];
#pragma unroll
            for (int ms = 0; ms < 4; ms++)
                af[ms] = *(const bf16x8*)(Ab + (size_t)(((wm * 4 + ms) * 2 + s) * 64 + lane) * 16);
#pragma unroll
            for (int ns = 0; ns < 2; ns++)
                bfr[ns] = *(const bf16x8*)(Bb + (size_t)(((wn * 2 + ns) * 2 + s) * 64 + lane) * 16);
#pragma unroll
            for (int ms = 0; ms < 4; ms++)
#pragma unroll
                for (int ns = 0; ns < 2; ns++)
                    acc[ms][ns] = __builtin_amdgcn_mfma_f32_32x32x16_bf16(
                        af[ms], bfr[ns], acc[ms][ns], 0, 0, 0);
        }
    }

    // ---- epilogue: block-local per-row max over all 256 codes ----
    float tmax[2] = {-1e30f, -1e30f};
#pragma unroll
    for (int ms = 0; ms < 4; ms++)
#pragma unroll
        for (int ns = 0; ns < 2; ns++)
#pragma unroll
            for (int r = 0; r < 16; r++)
                tmax[ns] = fmaxf(tmax[ns], acc[ms][ns][r]);
#pragma unroll
    for (int ns = 0; ns < 2; ns++)
        tmax[ns] = fmaxf(tmax[ns], __shfl_xor(tmax[ns], 32));

    __syncthreads();                 // GEMM LDS dead; reuse for rowmax + lcnt
    float* rmx  = (float*)smem;      // [2][256]: [wm][local row]
    int*   lcnt = (int*)(smem + 2048);   // [256] per-row slot counters
    if (lane < 32) {
        rmx[wm * 256 + wn * 64 + 0 * 32 + lane] = tmax[0];
        rmx[wm * 256 + wn * 64 + 1 * 32 + lane] = tmax[1];
    }
    if (tid < 256) lcnt[tid] = 0;
    __syncthreads();

    float thr[2];
#pragma unroll
    for (int ns = 0; ns < 2; ns++) {
        const int lr = wn * 64 + ns * 32 + m;
        thr[ns] = fmaxf(rmx[lr], rmx[256 + lr]) - MARGIN_T;
    }

    // ---- append keepers: LDS-atomic slot reservation + plain stores ----
#pragma unroll
    for (int ms = 0; ms < 4; ms++)
#pragma unroll
        for (int ns = 0; ns < 2; ns++)
#pragma unroll
            for (int r = 0; r < 16; r++) {
                float v = acc[ms][ns][r];
                if (v >= thr[ns]) {
                    const int lr = wn * 64 + ns * 32 + m;
                    int slot = atomicAdd(&lcnt[lr], 1);        // LDS atomic
                    if (slot < SLOTS) {
                        int code = codeBase + wm * 128 + ms * 32
                                 + ((r & 3) + 8 * (r >> 2) + 4 * half);
                        int b = __float_as_int(v);
                        unsigned key = (unsigned)b ^ ((unsigned)(b >> 31) | 0x80000000u);
                        unsigned entry = (key & 0xFFFFF000u) | (unsigned)code;
                        cand2[((size_t)(rowBase + lr) * 16 + cb) * SLOTS + slot] = entry;
                    }
                }
            }

    __syncthreads();
    if (tid < 256) {
        int cf = lcnt[tid];
        cnt8[(size_t)(rowBase + tid) * 16 + cb] =
            (cf > SLOTS) ? (unsigned char)255 : (unsigned char)cf;
        lmax[(size_t)(rowBase + tid) * 16 + cb] = fmaxf(rmx[tid], rmx[256 + tid]);
    }
}

// ---------------------------------------------------------------------------
// K_RESCORE v7: one WAVE per row.
// gm = exact fp32 global bf16-score row max = max of the 16 lmax entries.
// Full fallback ONLY if some block has cnt8==255 AND lmax >= gm - MARGIN
// (an overflowing block with lmax < gm-MARGIN provably contains no
// qualifying codes -> its stored entries are filtered out, overflow is
// harmless). The qualifying block's admission count equals the true
// candidate count (~1.5) -> fallback is ~1e-3 rare.
// Filter: keep entries with key lower-bound >= gm - MARGIN - 1e-4
// (20-bit key truncation slack) -> superset of the proven candidate set.
// Phase B: exact fp32 rescore (serial 256-FMA chain, ascending d, single
// accumulator = bit-identical to BLAS sgemm), (d,k) lexicographic
// tie-break. Staging via 8 NAMED float4 regs (R1-R5 used a float4 array
// that the compiler placed in scratch: 8KB spill write+read per batch per
// wave = the 1.5-59 GB WRITE_SIZE seen in counters).
// ---------------------------------------------------------------------------
__global__ __launch_bounds__(64) void k_rescore(
    const float* __restrict__ z, const float* __restrict__ w,
    const float* __restrict__ z2, const float* __restrict__ e2,
    const unsigned char* __restrict__ cnt8, const unsigned int* __restrict__ cand2,
    const float* __restrict__ lmax, int* __restrict__ idx_out)
{
#pragma clang fp contract(off)
    const int lane = threadIdx.x;
    const int n    = blockIdx.x;

    __shared__ float4   wst[RB * 65];   // 8320 B
    __shared__ float4   zst[64];        // 1 KB
    __shared__ unsigned sbuf[CAP];      // gathered packed entries
    __shared__ int      surv[CAP];      // filtered survivor codes

    zst[lane] = ((const float4*)(z + (size_t)n * D_DIM))[lane];

    // ---- gather + global-max reconstruction ----
    int   c  = 0;
    float lm = -1e30f;
    if (lane < 16) {
        c  = cnt8[(size_t)n * 16 + lane];
        lm = lmax[(size_t)n * 16 + lane];
    }
    float gm = lm;
#pragma unroll
    for (int off = 32; off > 0; off >>= 1)
        gm = fmaxf(gm, __shfl_xor(gm, off));          // wave-uniform exact max

    const bool needfull = __any((c == 255) && (lm >= gm - MARGIN_T));
    const int  cl = (c == 255) ? SLOTS : c;

    int inc = cl;
#pragma unroll
    for (int d = 1; d < 16; d <<= 1) {
        int t = __shfl_up(inc, d);
        if (lane >= d) inc += t;
    }
    const int excl = inc - cl;
    if (lane < 16 && cl > 0) {
        const unsigned* rp = cand2 + (size_t)n * 128 + lane * SLOTS;
        for (int j = 0; j < cl; j++) sbuf[excl + j] = rp[j];
    }
    const int total = __shfl(inc, 15);                // <= 128
    __syncthreads();

    // ---- filter to the exact global threshold ----
    const bool fallback = needfull || (total <= 0) || (total > CAP);
    int nt;
    if (!fallback) {
        const float thrF = gm - MARGIN_T - 1e-4f;     // key-truncation slack
        int tot = 0;
        for (int base = 0; base < total; base += 64) {
            bool keep = false;
            unsigned e = 0u;
            if (base + lane < total) {
                e = sbuf[base + lane];
                unsigned ky = e & 0xFFFFF000u;
                int b = (ky & 0x80000000u) ? (int)(ky ^ 0x80000000u) : (int)~ky;
                keep = (__int_as_float(b) >= thrF);
            }
            unsigned long long bal = __ballot(keep);
            int pos = tot + (int)__popcll(bal & ((1ull << lane) - 1ull));
            if (keep) surv[pos] = (int)(e & 0xFFFu);
            tot += (int)__popcll(bal);
        }
        nt = tot;            // >= 1 (the gm code is stored & passes)
    } else {
        nt = K_CODES;
    }
    __syncthreads();

    // ---- phase B: exact rescore (named regs -- no scratch spill) ----
    float bd = __builtin_inff(); int bk = K_CODES;
    const float z2v = z2[n];

    auto cidx = [&](int s) -> int {
        int kx = (s < nt) ? (fallback ? s : surv[s]) : 0;
        return ((unsigned)kx >= (unsigned)K_CODES) ? 0 : kx;
    };

    for (int base = 0; base < nt; base += RB) {
        int nb = nt - base; if (nb > RB) nb = RB;
        {
            int k0 = cidx(base + 0), k1 = cidx(base + 1);
            int k2 = cidx(base + 2), k3 = cidx(base + 3);
            int k4 = cidx(base + 4), k5 = cidx(base + 5);
            int k6 = cidx(base + 6), k7 = cidx(base + 7);
            float4 r0 = ((const float4*)(w + (size_t)k0 * D_DIM))[lane];
            float4 r1 = ((const float4*)(w + (size_t)k1 * D_DIM))[lane];
            float4 r2 = ((const float4*)(w + (size_t)k2 * D_DIM))[lane];
            float4 r3 = ((const float4*)(w + (size_t)k3 * D_DIM))[lane];
            float4 r4 = ((const float4*)(w + (size_t)k4 * D_DIM))[lane];
            float4 r5 = ((const float4*)(w + (size_t)k5 * D_DIM))[lane];
            float4 r6 = ((const float4*)(w + (size_t)k6 * D_DIM))[lane];
            float4 r7 = ((const float4*)(w + (size_t)k7 * D_DIM))[lane];
            wst[0 * 65 + lane] = r0;
            wst[1 * 65 + lane] = r1;
            wst[2 * 65 + lane] = r2;
            wst[3 * 65 + lane] = r3;
            wst[4 * 65 + lane] = r4;
            wst[5 * 65 + lane] = r5;
            wst[6 * 65 + lane] = r6;
            wst[7 * 65 + lane] = r7;
        }
        __syncthreads();
        if (lane < nb) {
            int k = fallback ? (base + lane) : surv[base + lane];
            if ((unsigned)k >= (unsigned)K_CODES) k = 0;   // defensive
            const float4* wp = &wst[lane * 65];
            float tacc = 0.0f;
#pragma unroll
            for (int d4 = 0; d4 < 64; d4++) {
                float4 wv = wp[d4];
                float4 zv = zst[d4];
                tacc = __builtin_fmaf(zv.x, wv.x, tacc);
                tacc = __builtin_fmaf(zv.y, wv.y, tacc);
                tacc = __builtin_fmaf(zv.z, wv.z, tacc);
                tacc = __builtin_fmaf(zv.w, wv.w, tacc);
            }
            float u  = z2v - 2.0f * tacc;   // 2*tacc exact -> single rounding
            float dv = u + e2[k];
            if (dv < bd || (dv == bd && k < bk)) { bd = dv; bk = k; }
        }
        __syncthreads();
    }

#pragma unroll
    for (int off = 1; off < 64; off <<= 1) {
        float od = __shfl_xor(bd, off);
        int   ok = __shfl_xor(bk, off);
        if (od < bd || (od == bd && ok < bk)) { bd = od; bk = ok; }
    }
    if (lane == 0) idx_out[n] = bk;
}

// ---------------------------------------------------------------------------
// K3: gather z_q, STE output, loss partials, counts + dw atomics.
// ---------------------------------------------------------------------------
__global__ void k3_scatter(const float* __restrict__ z, const float* __restrict__ w,
                           const int* __restrict__ idx_in,
                           float* __restrict__ counts, float* __restrict__ lossp,
                           float* __restrict__ dw, float* __restrict__ out_zq,
                           float* __restrict__ out_idx)
{
#pragma clang fp contract(off)
    const int n = blockIdx.x;
    const int t = threadIdx.x;
    int idx = idx_in[n];
    if (idx < 0) idx = 0;
    if (idx >= K_CODES) idx = K_CODES - 1;     // defensive clamp (no fault)
    if (t == 0) {
        out_idx[n] = (float)idx;
        atomicAdd(&counts[idx], 1.0f);
    }
    float zv = z[(size_t)n * D_DIM + t];
    float wq = w[(size_t)idx * D_DIM + t];
    out_zq[(size_t)n * D_DIM + t] = zv + (wq - zv);
    float df = zv - wq;
    float sq = df * df;
    atomicAdd(&dw[(size_t)idx * D_DIM + t], zv);

    __shared__ float red[256];
    red[t] = sq; __syncthreads();
    for (int s = 128; s > 0; s >>= 1) {
        if (t < s) red[t] += red[t + s];
        __syncthreads();
    }
    if (t == 0) lossp[n] = red[0];
}

// ---------------------------------------------------------------------------
// K4: vq_loss finalize + new_cs (Laplace smoothing). Single block, 1024 thr.
// ---------------------------------------------------------------------------
__global__ void k4_cs(const float* __restrict__ lossp, const float* __restrict__ counts,
                      const float* __restrict__ cs_in, float* __restrict__ out_loss,
                      float* __restrict__ out_cs)
{
#pragma clang fp contract(off)
    const int t = threadIdx.x;
    __shared__ float red[1024];
    __shared__ float pre[K_CODES];

    float s = 0.0f;
    for (int i = t; i < N_ROWS; i += 1024) s += lossp[i];
    red[t] = s; __syncthreads();
    for (int st = 512; st > 0; st >>= 1) {
        if (t < st) red[t] += red[t + st];
        __syncthreads();
    }
    if (t == 0) out_loss[0] = 0.25f * (red[0] / 8388608.0f);
    __syncthreads();

    const float DEC = 0.99f;
    const float OMD = (float)(1.0 - 0.99);
    float mine[4];
#pragma unroll
    for (int q = 0; q < 4; q++) {
        int k = t + q * 1024;
        float t1 = DEC * cs_in[k];
        float t2 = OMD * counts[k];
        float p = t1 + t2;
        pre[k] = p; mine[q] = p;
    }
    float psum = (mine[0] + mine[1]) + (mine[2] + mine[3]);
    red[t] = psum; __syncthreads();
    for (int st = 512; st > 0; st >>= 1) {
        if (t < st) red[t] += red[t + st];
        __syncthreads();
    }
    float nsum = red[0];
    const float KEPS = (float)(4096.0 * 1e-5);
    float denom = nsum + KEPS;
#pragma unroll
    for (int q = 0; q < 4; q++) {
        int k = t + q * 1024;
        float v = ((pre[k] + 1e-5f) / denom) * nsum;
        out_cs[k] = v;
    }
}

// ---------------------------------------------------------------------------
// K5: new_ema_w = 0.99*ema_w + 0.01*dw ; new_weight = new_ema_w / new_cs[k]
// ---------------------------------------------------------------------------
__global__ void k5_emaw(const float* __restrict__ ema_w, const float* __restrict__ dw,
                        const float* __restrict__ newcs, float* __restrict__ out_w,
                        float* __restrict__ out_emaw)
{
#pragma clang fp contract(off)
    const int i = blockIdx.x * 256 + threadIdx.x;
    const int k = i >> 8;
    const float OMD = (float)(1.0 - 0.99);
    float t1 = 0.99f * ema_w[i];
    float t2 = OMD * dw[i];
    float ne = t1 + t2;
    out_emaw[i] = ne;
    out_w[i] = ne / newcs[k];
}

extern "C" void kernel_launch(void* const* d_in, const int* in_sizes, int n_in,
                              void* d_out, int out_size, void* d_ws, size_t ws_size,
                              hipStream_t stream)
{
    const float* z    = (const float*)d_in[0];
    const float* w    = (const float*)d_in[1];
    const float* cs   = (const float*)d_in[2];
    const float* emaw = (const float*)d_in[3];

    float* out      = (float*)d_out;
    float* out_zq   = out;                    // 8388608
    float* out_idx  = out + 8388608;          // 32768
    float* out_loss = out + 8421376;          // 1
    float* out_w    = out + 8421377;          // 1048576
    float* out_cs   = out + 9469953;          // 4096
    float* out_emaw = out + 9474049;          // 1048576

    char* ws = (char*)d_ws;
    float*          counts  = (float*)(ws + WS_COUNTS);
    float*          lossp   = (float*)(ws + WS_LOSSP);
    int*            idx_int = (int*)  (ws + WS_IDX);
    float*          z2      = (float*)(ws + WS_Z2);
    float*          e2      = (float*)(ws + WS_E2);
    float*          dw      = (float*)(ws + WS_DW);

    // big scratch lives in d_out (consumed by rescore before k3/k4/k5 rewrite it)
    char* ob = (char*)d_out;
    unsigned short* zb    = (unsigned short*)(ob + DO_ZB);
    unsigned short* wb    = (unsigned short*)(ob + DO_WB);
    unsigned int*   cand2 = (unsigned int*)  (ob + DO_CAND);
    unsigned char*  cnt8  = (unsigned char*) (ob + DO_CNT8);
    float*          lmx   = (float*)         (ob + DO_LMAX);

    hipMemsetAsync(counts, 0, K_CODES * sizeof(float), stream);
    hipMemsetAsync(dw, 0, (size_t)K_CODES * D_DIM * sizeof(float), stream);

    k1_norms<<<(N_ROWS + K_CODES) / 256, 256, 0, stream>>>(z, w, z2, e2);

    // 4608 waves: (36864 rows / 64 rows-per-wave) * 8 kk-panels; 4 waves/block
    kconv<<<1152, 256, 0, stream>>>(z, w, zb, wb);

    dim3 g2(16, 128);   // x = code-block, y = row-block (swizzled in-kernel)
    k2_scan<<<g2, 512, 0, stream>>>(zb, wb, cnt8, cand2, lmx);

    k_rescore<<<N_ROWS, 64, 0, stream>>>(z, w, z2, e2, cnt8, cand2, lmx, idx_int);

    k3_scatter<<<N_ROWS, 256, 0, stream>>>(z, w, idx_int, counts, lossp,
                                           dw, out_zq, out_idx);

    k4_cs<<<1, 1024, 0, stream>>>(lossp, counts, cs, out_loss, out_cs);

    k5_emaw<<<K_CODES, 256, 0, stream>>>(emaw, dw, out_cs, out_w, out_emaw);
}

// Round 7
// 591.785 us; speedup vs baseline: 31.0226x; 2.3449x over previous
//
#include <hip/hip_runtime.h>
#include <hip/hip_bf16.h>

#define N_ROWS 32768
#define K_CODES 4096
#define D_DIM 256
#define CAP 128
#define MARGIN_T 1e-3f
#define RB 8
#define SLOTS 8

// ---- d_ws layout (bytes) -- total 4,882,432 ----
#define WS_COUNTS    0          // float[4096]
#define WS_LOSSP     16384      // float[32768]
#define WS_IDX       147456     // int[32768]
#define WS_Z2        278528     // float[32768]
#define WS_E2        409600     // float[4096]
#define WS_DW        688128     // float[1048576] -> ends 4882432

// ---- d_out scratch (all regions consumed by rescore before k3/k4/k5 rewrite) ----
#define DO_ZB        0          // ushort[32768*256] = 16 MB (panel layout)
#define DO_WB        16777216   // ushort[4096*256]  =  2 MB (panel layout)
#define DO_CAND      18874368   // uint[32768][16][8] = 16 MB -> ends 35651584
#define DO_CNT8      35651584   // uchar[32768][16]  = 512 KB -> ends 36175872
#define DO_LMAX      36175872   // float[32768][16]  =   2 MB -> ends 38273024 (< 42.09 MB)

typedef __attribute__((ext_vector_type(8)))  short bf16x8;
typedef __attribute__((ext_vector_type(16))) float f32x16;
typedef __attribute__((ext_vector_type(8)))  unsigned short us8;

// ---------------------------------------------------------------------------
// K1: z2/e2 with numpy's exact pairwise structure (proven in R1)
// ---------------------------------------------------------------------------
__global__ void k1_norms(const float* __restrict__ z, const float* __restrict__ w,
                         float* __restrict__ z2, float* __restrict__ e2)
{
#pragma clang fp contract(off)
    int gid = blockIdx.x * blockDim.x + threadIdx.x;
    const float* row;
    float* outp;
    if (gid < N_ROWS) { row = z + (size_t)gid * D_DIM; outp = z2 + gid; }
    else if (gid < N_ROWS + K_CODES) { row = w + (size_t)(gid - N_ROWS) * D_DIM; outp = e2 + (gid - N_ROWS); }
    else return;

    float total = 0.0f;
    for (int half = 0; half < 2; half++) {
        const float* x = row + half * 128;
        float r[8];
#pragma unroll
        for (int j = 0; j < 8; j++) { float v = x[j]; r[j] = v * v; }
        for (int i = 8; i < 128; i += 8) {
#pragma unroll
            for (int j = 0; j < 8; j++) { float v = x[i + j]; r[j] += v * v; }
        }
        float s = ((r[0] + r[1]) + (r[2] + r[3])) + ((r[4] + r[5]) + (r[6] + r[7]));
        if (half == 0) total = s; else total = total + s;
    }
    *outp = total;
}

// ---------------------------------------------------------------------------
// KCONV v2 (proven R4): fp32 -> bf16 (RNE) in "LDS-image" PANEL layout so
// k2's staging is a straight contiguous copy. Bit-identical LDS bytes vs R3.
// ---------------------------------------------------------------------------
__device__ inline unsigned short f2b(float f) {
    __hip_bfloat16 h = __float2bfloat16(f);
    return *(unsigned short*)&h;
}

__global__ void kconv(const float* __restrict__ z, const float* __restrict__ w,
                      unsigned short* __restrict__ zb, unsigned short* __restrict__ wb)
{
    const int lane  = threadIdx.x & 63;
    const int gwave = blockIdx.x * 4 + (threadIdx.x >> 6);   // 0..4607
    const int kk    = gwave & 7;
    const int row   = (gwave >> 3) * 64 + lane;              // 0..36863
    const float* src;
    unsigned short* panel;
    int g;
    if (row < N_ROWS) {
        src   = z + (size_t)row * D_DIM;
        panel = zb + ((size_t)((row >> 8) * 8 + kk) << 13);
        g     = (row >> 5) & 7;
    } else {
        int c = row - N_ROWS;
        src   = w + (size_t)c * D_DIM;
        panel = wb + ((size_t)((c >> 8) * 8 + kk) << 13);
        g     = (c >> 5) & 7;
    }
    const int r31 = row & 31;
    const float* s0 = src + kk * 32;
#pragma unroll
    for (int s = 0; s < 2; s++)
#pragma unroll
        for (int h = 0; h < 2; h++) {
            float4 a = *(const float4*)(s0 + s * 16 + h * 8);
            float4 b = *(const float4*)(s0 + s * 16 + h * 8 + 4);
            us8 o;
            o[0] = f2b(a.x); o[1] = f2b(a.y); o[2] = f2b(a.z); o[3] = f2b(a.w);
            o[4] = f2b(b.x); o[5] = f2b(b.y); o[6] = f2b(b.z); o[7] = f2b(b.w);
            *(us8*)(panel + (((g * 2 + s) * 64 + h * 32 + r31) << 3)) = o;
        }
}

// ---------------------------------------------------------------------------
// async global->LDS, 16B per lane. LDS dest = wave-uniform base + lane*16.
// ---------------------------------------------------------------------------
__device__ inline void gload16(const void* g, void* l)
{
    __builtin_amdgcn_global_load_lds(
        (const __attribute__((address_space(1))) unsigned int*)g,
        (__attribute__((address_space(3))) unsigned int*)l,
        16, 0, 0);
}

// ---------------------------------------------------------------------------
// K2 v5.1 (unchanged from R6 -- inferred <=150us there): 256x256-tile bf16
// MFMA GEMM, atomic-free append (LDS-atomic slot reservation, per-(row,cb)
// 8-slot regions, plain stores), exact fp32 block-local row max to lmax.
// ---------------------------------------------------------------------------
__global__ __launch_bounds__(512, 2) void k2_scan(
    const unsigned short* __restrict__ zb, const unsigned short* __restrict__ wb,
    unsigned char* __restrict__ cnt8, unsigned int* __restrict__ cand2,
    float* __restrict__ lmax)
{
    __shared__ char smem[65536];
    const int tid  = threadIdx.x;
    const int lane = tid & 63;
    const int wid  = tid >> 6;     // 0..7
    const int wm   = wid >> 2;     // code-wave 0..1
    const int wn   = wid & 3;      // row-wave 0..3
    const int m    = lane & 31;
    const int half = lane >> 5;

    // bijective XCD swizzle: XCD(r_hw) == o/256 (proven R3/R4: FETCH 17MB)
    const int r_hw = blockIdx.y * 16 + blockIdx.x;
    const int o    = (r_hw & 7) * 256 + (r_hw >> 3);
    const int cb   = o & 15;       // code-block 0..15
    const int rb   = o >> 4;       // row-block  0..127
    const int rowBase  = rb * 256;
    const int codeBase = cb * 256;

    // linear panel copy: A panel (wb) and B panel (zb) for window kk.
    auto stage = [&](int kk, int buf) {
        char* Ab = smem + buf * 32768;
        char* Bb = Ab + 16384;
        const unsigned short* Ap = wb + ((size_t)(cb * 8 + kk) << 13);
        const unsigned short* Bp = zb + ((size_t)(rb * 8 + kk) << 13);
#pragma unroll
        for (int i = 0; i < 2; i++) {
            gload16(Ap + (size_t)((i * 512 + tid) << 3), Ab + (size_t)(i * 512 + tid) * 16);
            gload16(Bp + (size_t)((i * 512 + tid) << 3), Bb + (size_t)(i * 512 + tid) * 16);
        }
    };

    f32x16 acc[4][2];
    {
        f32x16 zz = {};
#pragma unroll
        for (int ms = 0; ms < 4; ms++)
#pragma unroll
            for (int ns = 0; ns < 2; ns++) acc[ms][ns] = zz;
    }

    stage(0, 0);

    for (int kk = 0; kk < 8; kk++) {
        const int buf = kk & 1;
        __syncthreads();                       // drains vmcnt -> buf ready
        if (kk + 1 < 8) stage(kk + 1, buf ^ 1);
        const char* Ab = smem + buf * 32768;
        const char* Bb = Ab + 16384;
#pragma unroll
        for (int s = 0; s < 2; s++) {
            bf16x8 af[4], bfr[2];
#pragma unroll
            for (int ms = 0; ms < 4; ms++)
                af[ms] = *(const bf16x8*)(Ab + (size_t)(((wm * 4 + ms) * 2 + s) * 64 + lane) * 16);
#pragma unroll
            for (int ns = 0; ns < 2; ns++)
                bfr[ns] = *(const bf16x8*)(Bb + (size_t)(((wn * 2 + ns) * 2 + s) * 64 + lane) * 16);
#pragma unroll
            for (int ms = 0; ms < 4; ms++)
#pragma unroll
                for (int ns = 0; ns < 2; ns++)
                    acc[ms][ns] = __builtin_amdgcn_mfma_f32_32x32x16_bf16(
                        af[ms], bfr[ns], acc[ms][ns], 0, 0, 0);
        }
    }

    // ---- epilogue: block-local per-row max over all 256 codes ----
    float tmax[2] = {-1e30f, -1e30f};
#pragma unroll
    for (int ms = 0; ms < 4; ms++)
#pragma unroll
        for (int ns = 0; ns < 2; ns++)
#pragma unroll
            for (int r = 0; r < 16; r++)
                tmax[ns] = fmaxf(tmax[ns], acc[ms][ns][r]);
#pragma unroll
    for (int ns = 0; ns < 2; ns++)
        tmax[ns] = fmaxf(tmax[ns], __shfl_xor(tmax[ns], 32));

    __syncthreads();                 // GEMM LDS dead; reuse for rowmax + lcnt
    float* rmx  = (float*)smem;      // [2][256]: [wm][local row]
    int*   lcnt = (int*)(smem + 2048);   // [256] per-row slot counters
    if (lane < 32) {
        rmx[wm * 256 + wn * 64 + 0 * 32 + lane] = tmax[0];
        rmx[wm * 256 + wn * 64 + 1 * 32 + lane] = tmax[1];
    }
    if (tid < 256) lcnt[tid] = 0;
    __syncthreads();

    float thr[2];
#pragma unroll
    for (int ns = 0; ns < 2; ns++) {
        const int lr = wn * 64 + ns * 32 + m;
        thr[ns] = fmaxf(rmx[lr], rmx[256 + lr]) - MARGIN_T;
    }

    // ---- append keepers: LDS-atomic slot reservation + plain stores ----
#pragma unroll
    for (int ms = 0; ms < 4; ms++)
#pragma unroll
        for (int ns = 0; ns < 2; ns++)
#pragma unroll
            for (int r = 0; r < 16; r++) {
                float v = acc[ms][ns][r];
                if (v >= thr[ns]) {
                    const int lr = wn * 64 + ns * 32 + m;
                    int slot = atomicAdd(&lcnt[lr], 1);        // LDS atomic
                    if (slot < SLOTS) {
                        int code = codeBase + wm * 128 + ms * 32
                                 + ((r & 3) + 8 * (r >> 2) + 4 * half);
                        int b = __float_as_int(v);
                        unsigned key = (unsigned)b ^ ((unsigned)(b >> 31) | 0x80000000u);
                        unsigned entry = (key & 0xFFFFF000u) | (unsigned)code;
                        cand2[((size_t)(rowBase + lr) * 16 + cb) * SLOTS + slot] = entry;
                    }
                }
            }

    __syncthreads();
    if (tid < 256) {
        int cf = lcnt[tid];
        cnt8[(size_t)(rowBase + tid) * 16 + cb] =
            (cf > SLOTS) ? (unsigned char)255 : (unsigned char)cf;
        lmax[(size_t)(rowBase + tid) * 16 + cb] = fmaxf(rmx[tid], rmx[256 + tid]);
    }
}

// ---------------------------------------------------------------------------
// K_RESCORE v8: one WAVE per row.
// gm = exact fp32 global bf16-score row max = max of 16 lmax entries.
// Full scan ONLY if an overflowed block (cnt8==255) has lmax >= gm-MARGIN.
//
// NEW (R6 post-mortem): the full scan is LANE-PARALLEL. R6's 8-codes/batch
// one-wave fallback took ~400us/row (8/64 lanes, 512 serial batches) and a
// handful of such rows WAS the whole 1140us kernel (Occupancy 2.45%). Now
// each lane owns 64 codes with TWO interleaved exact serial chains (hides
// the 4-cyc FMA dep at 2-cyc SIMD issue): ~16us/row, all lanes busy.
// Chain arithmetic per code is IDENTICAL (ascending d, single accumulator,
// u = z2 - 2*t; dv = u + e2) -> bit-identical distances; per-lane sequential
// visit order is ascending k and the (dv,k) lexicographic butterfly gives
// the global first-index argmin.
// Non-fallback path unchanged from R6 (named regs, no scratch).
// ---------------------------------------------------------------------------
__global__ __launch_bounds__(64) void k_rescore(
    const float* __restrict__ z, const float* __restrict__ w,
    const float* __restrict__ z2, const float* __restrict__ e2,
    const unsigned char* __restrict__ cnt8, const unsigned int* __restrict__ cand2,
    const float* __restrict__ lmax, int* __restrict__ idx_out)
{
#pragma clang fp contract(off)
    const int lane = threadIdx.x;
    const int n    = blockIdx.x;

    __shared__ float4   wst[RB * 65];   // 8320 B
    __shared__ float4   zst[64];        // 1 KB
    __shared__ unsigned sbuf[CAP];      // gathered packed entries
    __shared__ int      surv[CAP];      // filtered survivor codes

    zst[lane] = ((const float4*)(z + (size_t)n * D_DIM))[lane];

    // ---- global-max reconstruction ----
    int   c  = 0;
    float lm = -1e30f;
    if (lane < 16) {
        c  = cnt8[(size_t)n * 16 + lane];
        lm = lmax[(size_t)n * 16 + lane];
    }
    float gm = lm;
#pragma unroll
    for (int off = 32; off > 0; off >>= 1)
        gm = fmaxf(gm, __shfl_xor(gm, off));          // wave-uniform exact max

    const bool needfull = __any((c == 255) && (lm >= gm - MARGIN_T));

    float bd = __builtin_inff(); int bk = K_CODES;
    const float z2v = z2[n];

    if (needfull) {
        // ---- lane-parallel exact full scan (wave-uniform branch) ----
        __syncthreads();                               // zst visible
        for (int k0 = lane; k0 < K_CODES; k0 += 128) {
            const int kA = k0, kB = k0 + 64;
            const float4* wA = (const float4*)(w + (size_t)kA * D_DIM);
            const float4* wB = (const float4*)(w + (size_t)kB * D_DIM);
            float ta = 0.0f, tb = 0.0f;
#pragma unroll 8
            for (int d4 = 0; d4 < 64; d4++) {
                float4 zv = zst[d4];                   // LDS broadcast
                float4 wa = wA[d4];
                float4 wb2 = wB[d4];
                ta = __builtin_fmaf(zv.x, wa.x, ta);
                tb = __builtin_fmaf(zv.x, wb2.x, tb);
                ta = __builtin_fmaf(zv.y, wa.y, ta);
                tb = __builtin_fmaf(zv.y, wb2.y, tb);
                ta = __builtin_fmaf(zv.z, wa.z, ta);
                tb = __builtin_fmaf(zv.z, wb2.z, tb);
                ta = __builtin_fmaf(zv.w, wa.w, ta);
                tb = __builtin_fmaf(zv.w, wb2.w, tb);
            }
            float uA = z2v - 2.0f * ta;
            float dA = uA + e2[kA];
            float uB = z2v - 2.0f * tb;
            float dB = uB + e2[kB];
            if (dA < bd || (dA == bd && kA < bk)) { bd = dA; bk = kA; }
            if (dB < bd || (dB == bd && kB < bk)) { bd = dB; bk = kB; }
        }
    } else {
        // ---- gather ----
        const int cl = (c == 255) ? SLOTS : c;
        int inc = cl;
#pragma unroll
        for (int d = 1; d < 16; d <<= 1) {
            int t = __shfl_up(inc, d);
            if (lane >= d) inc += t;
        }
        const int excl = inc - cl;
        if (lane < 16 && cl > 0) {
            const unsigned* rp = cand2 + (size_t)n * 128 + lane * SLOTS;
            for (int j = 0; j < cl; j++) sbuf[excl + j] = rp[j];
        }
        const int total = __shfl(inc, 15);            // <= 128
        __syncthreads();

        // ---- filter to the exact global threshold ----
        int nt = 0;
        {
            const float thrF = gm - MARGIN_T - 1e-4f; // key-truncation slack
            for (int base = 0; base < total; base += 64) {
                bool keep = false;
                unsigned e = 0u;
                if (base + lane < total) {
                    e = sbuf[base + lane];
                    unsigned ky = e & 0xFFFFF000u;
                    int b = (ky & 0x80000000u) ? (int)(ky ^ 0x80000000u) : (int)~ky;
                    keep = (__int_as_float(b) >= thrF);
                }
                unsigned long long bal = __ballot(keep);
                int pos = nt + (int)__popcll(bal & ((1ull << lane) - 1ull));
                if (keep) surv[pos] = (int)(e & 0xFFFu);
                nt += (int)__popcll(bal);
            }
            if (nt < 1) nt = 0;                       // defensive (gm code always stored)
        }
        __syncthreads();

        // ---- exact rescore of survivors (named regs -- no scratch) ----
        auto cidx = [&](int s) -> int {
            int kx = (s < nt) ? surv[s] : 0;
            return ((unsigned)kx >= (unsigned)K_CODES) ? 0 : kx;
        };

        for (int base = 0; base < nt; base += RB) {
            int nb = nt - base; if (nb > RB) nb = RB;
            {
                int k0 = cidx(base + 0), k1 = cidx(base + 1);
                int k2 = cidx(base + 2), k3 = cidx(base + 3);
                int k4 = cidx(base + 4), k5 = cidx(base + 5);
                int k6 = cidx(base + 6), k7 = cidx(base + 7);
                float4 r0 = ((const float4*)(w + (size_t)k0 * D_DIM))[lane];
                float4 r1 = ((const float4*)(w + (size_t)k1 * D_DIM))[lane];
                float4 r2 = ((const float4*)(w + (size_t)k2 * D_DIM))[lane];
                float4 r3 = ((const float4*)(w + (size_t)k3 * D_DIM))[lane];
                float4 r4 = ((const float4*)(w + (size_t)k4 * D_DIM))[lane];
                float4 r5 = ((const float4*)(w + (size_t)k5 * D_DIM))[lane];
                float4 r6 = ((const float4*)(w + (size_t)k6 * D_DIM))[lane];
                float4 r7 = ((const float4*)(w + (size_t)k7 * D_DIM))[lane];
                wst[0 * 65 + lane] = r0;
                wst[1 * 65 + lane] = r1;
                wst[2 * 65 + lane] = r2;
                wst[3 * 65 + lane] = r3;
                wst[4 * 65 + lane] = r4;
                wst[5 * 65 + lane] = r5;
                wst[6 * 65 + lane] = r6;
                wst[7 * 65 + lane] = r7;
            }
            __syncthreads();
            if (lane < nb) {
                int k = surv[base + lane];
                if ((unsigned)k >= (unsigned)K_CODES) k = 0;   // defensive
                const float4* wp = &wst[lane * 65];
                float tacc = 0.0f;
#pragma unroll
                for (int d4 = 0; d4 < 64; d4++) {
                    float4 wv = wp[d4];
                    float4 zv = zst[d4];
                    tacc = __builtin_fmaf(zv.x, wv.x, tacc);
                    tacc = __builtin_fmaf(zv.y, wv.y, tacc);
                    tacc = __builtin_fmaf(zv.z, wv.z, tacc);
                    tacc = __builtin_fmaf(zv.w, wv.w, tacc);
                }
                float u  = z2v - 2.0f * tacc;   // 2*tacc exact -> single rounding
                float dv = u + e2[k];
                if (dv < bd || (dv == bd && k < bk)) { bd = dv; bk = k; }
            }
            __syncthreads();
        }
    }

#pragma unroll
    for (int off = 1; off < 64; off <<= 1) {
        float od = __shfl_xor(bd, off);
        int   ok = __shfl_xor(bk, off);
        if (od < bd || (od == bd && ok < bk)) { bd = od; bk = ok; }
    }
    if (lane == 0) idx_out[n] = (bk < K_CODES) ? bk : 0;
}

// ---------------------------------------------------------------------------
// K3: gather z_q, STE output, loss partials, counts + dw atomics.
// ---------------------------------------------------------------------------
__global__ void k3_scatter(const float* __restrict__ z, const float* __restrict__ w,
                           const int* __restrict__ idx_in,
                           float* __restrict__ counts, float* __restrict__ lossp,
                           float* __restrict__ dw, float* __restrict__ out_zq,
                           float* __restrict__ out_idx)
{
#pragma clang fp contract(off)
    const int n = blockIdx.x;
    const int t = threadIdx.x;
    int idx = idx_in[n];
    if (idx < 0) idx = 0;
    if (idx >= K_CODES) idx = K_CODES - 1;     // defensive clamp (no fault)
    if (t == 0) {
        out_idx[n] = (float)idx;
        atomicAdd(&counts[idx], 1.0f);
    }
    float zv = z[(size_t)n * D_DIM + t];
    float wq = w[(size_t)idx * D_DIM + t];
    out_zq[(size_t)n * D_DIM + t] = zv + (wq - zv);
    float df = zv - wq;
    float sq = df * df;
    atomicAdd(&dw[(size_t)idx * D_DIM + t], zv);

    __shared__ float red[256];
    red[t] = sq; __syncthreads();
    for (int s = 128; s > 0; s >>= 1) {
        if (t < s) red[t] += red[t + s];
        __syncthreads();
    }
    if (t == 0) lossp[n] = red[0];
}

// ---------------------------------------------------------------------------
// K4: vq_loss finalize + new_cs (Laplace smoothing). Single block, 1024 thr.
// ---------------------------------------------------------------------------
__global__ void k4_cs(const float* __restrict__ lossp, const float* __restrict__ counts,
                      const float* __restrict__ cs_in, float* __restrict__ out_loss,
                      float* __restrict__ out_cs)
{
#pragma clang fp contract(off)
    const int t = threadIdx.x;
    __shared__ float red[1024];
    __shared__ float pre[K_CODES];

    float s = 0.0f;
    for (int i = t; i < N_ROWS; i += 1024) s += lossp[i];
    red[t] = s; __syncthreads();
    for (int st = 512; st > 0; st >>= 1) {
        if (t < st) red[t] += red[t + st];
        __syncthreads();
    }
    if (t == 0) out_loss[0] = 0.25f * (red[0] / 8388608.0f);
    __syncthreads();

    const float DEC = 0.99f;
    const float OMD = (float)(1.0 - 0.99);
    float mine[4];
#pragma unroll
    for (int q = 0; q < 4; q++) {
        int k = t + q * 1024;
        float t1 = DEC * cs_in[k];
        float t2 = OMD * counts[k];
        float p = t1 + t2;
        pre[k] = p; mine[q] = p;
    }
    float psum = (mine[0] + mine[1]) + (mine[2] + mine[3]);
    red[t] = psum; __syncthreads();
    for (int st = 512; st > 0; st >>= 1) {
        if (t < st) red[t] += red[t + st];
        __syncthreads();
    }
    float nsum = red[0];
    const float KEPS = (float)(4096.0 * 1e-5);
    float denom = nsum + KEPS;
#pragma unroll
    for (int q = 0; q < 4; q++) {
        int k = t + q * 1024;
        float v = ((pre[k] + 1e-5f) / denom) * nsum;
        out_cs[k] = v;
    }
}

// ---------------------------------------------------------------------------
// K5: new_ema_w = 0.99*ema_w + 0.01*dw ; new_weight = new_ema_w / new_cs[k]
// ---------------------------------------------------------------------------
__global__ void k5_emaw(const float* __restrict__ ema_w, const float* __restrict__ dw,
                        const float* __restrict__ newcs, float* __restrict__ out_w,
                        float* __restrict__ out_emaw)
{
#pragma clang fp contract(off)
    const int i = blockIdx.x * 256 + threadIdx.x;
    const int k = i >> 8;
    const float OMD = (float)(1.0 - 0.99);
    float t1 = 0.99f * ema_w[i];
    float t2 = OMD * dw[i];
    float ne = t1 + t2;
    out_emaw[i] = ne;
    out_w[i] = ne / newcs[k];
}

extern "C" void kernel_launch(void* const* d_in, const int* in_sizes, int n_in,
                              void* d_out, int out_size, void* d_ws, size_t ws_size,
                              hipStream_t stream)
{
    const float* z    = (const float*)d_in[0];
    const float* w    = (const float*)d_in[1];
    const float* cs   = (const float*)d_in[2];
    const float* emaw = (const float*)d_in[3];

    float* out      = (float*)d_out;
    float* out_zq   = out;                    // 8388608
    float* out_idx  = out + 8388608;          // 32768
    float* out_loss = out + 8421376;          // 1
    float* out_w    = out + 8421377;          // 1048576
    float* out_cs   = out + 9469953;          // 4096
    float* out_emaw = out + 9474049;          // 1048576

    char* ws = (char*)d_ws;
    float*          counts  = (float*)(ws + WS_COUNTS);
    float*          lossp   = (float*)(ws + WS_LOSSP);
    int*            idx_int = (int*)  (ws + WS_IDX);
    float*          z2      = (float*)(ws + WS_Z2);
    float*          e2      = (float*)(ws + WS_E2);
    float*          dw      = (float*)(ws + WS_DW);

    // big scratch lives in d_out (consumed by rescore before k3/k4/k5 rewrite it)
    char* ob = (char*)d_out;
    unsigned short* zb    = (unsigned short*)(ob + DO_ZB);
    unsigned short* wb    = (unsigned short*)(ob + DO_WB);
    unsigned int*   cand2 = (unsigned int*)  (ob + DO_CAND);
    unsigned char*  cnt8  = (unsigned char*) (ob + DO_CNT8);
    float*          lmx   = (float*)         (ob + DO_LMAX);

    hipMemsetAsync(counts, 0, K_CODES * sizeof(float), stream);
    hipMemsetAsync(dw, 0, (size_t)K_CODES * D_DIM * sizeof(float), stream);

    k1_norms<<<(N_ROWS + K_CODES) / 256, 256, 0, stream>>>(z, w, z2, e2);

    // 4608 waves: (36864 rows / 64 rows-per-wave) * 8 kk-panels; 4 waves/block
    kconv<<<1152, 256, 0, stream>>>(z, w, zb, wb);

    dim3 g2(16, 128);   // x = code-block, y = row-block (swizzled in-kernel)
    k2_scan<<<g2, 512, 0, stream>>>(zb, wb, cnt8, cand2, lmx);

    k_rescore<<<N_ROWS, 64, 0, stream>>>(z, w, z2, e2, cnt8, cand2, lmx, idx_int);

    k3_scatter<<<N_ROWS, 256, 0, stream>>>(z, w, idx_int, counts, lossp,
                                           dw, out_zq, out_idx);

    k4_cs<<<1, 1024, 0, stream>>>(lossp, counts, cs, out_loss, out_cs);

    k5_emaw<<<K_CODES, 256, 0, stream>>>(emaw, dw, out_cs, out_w, out_emaw);
}

// Round 8
// 570.791 us; speedup vs baseline: 32.1636x; 1.0368x over previous
//
#include <hip/hip_runtime.h>
#include <hip/hip_bf16.h>

#define N_ROWS 32768
#define K_CODES 4096
#define D_DIM 256
#define CAP 128
#define MARGIN_T 1e-3f
#define SLOTS 8

// ---- d_ws layout (bytes) -- total 4,882,432 ----
#define WS_COUNTS    0          // float[4096]
#define WS_LOSSP     16384      // float[32768]
#define WS_IDX       147456     // int[32768]
#define WS_Z2        278528     // float[32768]
#define WS_E2        409600     // float[4096]
#define WS_DW        688128     // float[1048576] -> ends 4882432

// ---- d_out scratch (all regions consumed by rescore before k3/k4/k5 rewrite) ----
#define DO_ZB        0          // ushort[32768*256] = 16 MB (panel layout)
#define DO_WB        16777216   // ushort[4096*256]  =  2 MB (panel layout)
#define DO_CAND      18874368   // uint[32768][16][8] = 16 MB -> ends 35651584
#define DO_CNT8      35651584   // uchar[32768][16]  = 512 KB -> ends 36175872
#define DO_LMAX      36175872   // float[32768][16]  =   2 MB -> ends 38273024 (< 42.09 MB)

typedef __attribute__((ext_vector_type(8)))  short bf16x8;
typedef __attribute__((ext_vector_type(16))) float f32x16;
typedef __attribute__((ext_vector_type(8)))  unsigned short us8;

// ---------------------------------------------------------------------------
// K1: z2/e2 with numpy's exact pairwise structure (proven in R1)
// ---------------------------------------------------------------------------
__global__ void k1_norms(const float* __restrict__ z, const float* __restrict__ w,
                         float* __restrict__ z2, float* __restrict__ e2)
{
#pragma clang fp contract(off)
    int gid = blockIdx.x * blockDim.x + threadIdx.x;
    const float* row;
    float* outp;
    if (gid < N_ROWS) { row = z + (size_t)gid * D_DIM; outp = z2 + gid; }
    else if (gid < N_ROWS + K_CODES) { row = w + (size_t)(gid - N_ROWS) * D_DIM; outp = e2 + (gid - N_ROWS); }
    else return;

    float total = 0.0f;
    for (int half = 0; half < 2; half++) {
        const float* x = row + half * 128;
        float r[8];
#pragma unroll
        for (int j = 0; j < 8; j++) { float v = x[j]; r[j] = v * v; }
        for (int i = 8; i < 128; i += 8) {
#pragma unroll
            for (int j = 0; j < 8; j++) { float v = x[i + j]; r[j] += v * v; }
        }
        float s = ((r[0] + r[1]) + (r[2] + r[3])) + ((r[4] + r[5]) + (r[6] + r[7]));
        if (half == 0) total = s; else total = total + s;
    }
    *outp = total;
}

// ---------------------------------------------------------------------------
// KCONV v2 (proven R4): fp32 -> bf16 (RNE) in "LDS-image" PANEL layout so
// k2's staging is a straight contiguous copy. Bit-identical LDS bytes vs R3.
// ---------------------------------------------------------------------------
__device__ inline unsigned short f2b(float f) {
    __hip_bfloat16 h = __float2bfloat16(f);
    return *(unsigned short*)&h;
}

__global__ void kconv(const float* __restrict__ z, const float* __restrict__ w,
                      unsigned short* __restrict__ zb, unsigned short* __restrict__ wb)
{
    const int lane  = threadIdx.x & 63;
    const int gwave = blockIdx.x * 4 + (threadIdx.x >> 6);   // 0..4607
    const int kk    = gwave & 7;
    const int row   = (gwave >> 3) * 64 + lane;              // 0..36863
    const float* src;
    unsigned short* panel;
    int g;
    if (row < N_ROWS) {
        src   = z + (size_t)row * D_DIM;
        panel = zb + ((size_t)((row >> 8) * 8 + kk) << 13);
        g     = (row >> 5) & 7;
    } else {
        int c = row - N_ROWS;
        src   = w + (size_t)c * D_DIM;
        panel = wb + ((size_t)((c >> 8) * 8 + kk) << 13);
        g     = (c >> 5) & 7;
    }
    const int r31 = row & 31;
    const float* s0 = src + kk * 32;
#pragma unroll
    for (int s = 0; s < 2; s++)
#pragma unroll
        for (int h = 0; h < 2; h++) {
            float4 a = *(const float4*)(s0 + s * 16 + h * 8);
            float4 b = *(const float4*)(s0 + s * 16 + h * 8 + 4);
            us8 o;
            o[0] = f2b(a.x); o[1] = f2b(a.y); o[2] = f2b(a.z); o[3] = f2b(a.w);
            o[4] = f2b(b.x); o[5] = f2b(b.y); o[6] = f2b(b.z); o[7] = f2b(b.w);
            *(us8*)(panel + (((g * 2 + s) * 64 + h * 32 + r31) << 3)) = o;
        }
}

// ---------------------------------------------------------------------------
// async global->LDS, 16B per lane. LDS dest = wave-uniform base + lane*16.
// ---------------------------------------------------------------------------
__device__ inline void gload16(const void* g, void* l)
{
    __builtin_amdgcn_global_load_lds(
        (const __attribute__((address_space(1))) unsigned int*)g,
        (__attribute__((address_space(3))) unsigned int*)l,
        16, 0, 0);
}

// ---------------------------------------------------------------------------
// K2 v5.1 (unchanged from R6/R7): 256x256-tile bf16 MFMA GEMM, atomic-free
// append (LDS-atomic slot reservation, per-(row,cb) 8-slot regions, plain
// stores), exact fp32 block-local row max to lmax.
// ---------------------------------------------------------------------------
__global__ __launch_bounds__(512, 2) void k2_scan(
    const unsigned short* __restrict__ zb, const unsigned short* __restrict__ wb,
    unsigned char* __restrict__ cnt8, unsigned int* __restrict__ cand2,
    float* __restrict__ lmax)
{
    __shared__ char smem[65536];
    const int tid  = threadIdx.x;
    const int lane = tid & 63;
    const int wid  = tid >> 6;     // 0..7
    const int wm   = wid >> 2;     // code-wave 0..1
    const int wn   = wid & 3;      // row-wave 0..3
    const int m    = lane & 31;
    const int half = lane >> 5;

    // bijective XCD swizzle: XCD(r_hw) == o/256 (proven R3/R4: FETCH 17MB)
    const int r_hw = blockIdx.y * 16 + blockIdx.x;
    const int o    = (r_hw & 7) * 256 + (r_hw >> 3);
    const int cb   = o & 15;       // code-block 0..15
    const int rb   = o >> 4;       // row-block  0..127
    const int rowBase  = rb * 256;
    const int codeBase = cb * 256;

    // linear panel copy: A panel (wb) and B panel (zb) for window kk.
    auto stage = [&](int kk, int buf) {
        char* Ab = smem + buf * 32768;
        char* Bb = Ab + 16384;
        const unsigned short* Ap = wb + ((size_t)(cb * 8 + kk) << 13);
        const unsigned short* Bp = zb + ((size_t)(rb * 8 + kk) << 13);
#pragma unroll
        for (int i = 0; i < 2; i++) {
            gload16(Ap + (size_t)((i * 512 + tid) << 3), Ab + (size_t)(i * 512 + tid) * 16);
            gload16(Bp + (size_t)((i * 512 + tid) << 3), Bb + (size_t)(i * 512 + tid) * 16);
        }
    };

    f32x16 acc[4][2];
    {
        f32x16 zz = {};
#pragma unroll
        for (int ms = 0; ms < 4; ms++)
#pragma unroll
            for (int ns = 0; ns < 2; ns++) acc[ms][ns] = zz;
    }

    stage(0, 0);

    for (int kk = 0; kk < 8; kk++) {
        const int buf = kk & 1;
        __syncthreads();                       // drains vmcnt -> buf ready
        if (kk + 1 < 8) stage(kk + 1, buf ^ 1);
        const char* Ab = smem + buf * 32768;
        const char* Bb = Ab + 16384;
#pragma unroll
        for (int s = 0; s < 2; s++) {
            bf16x8 af[4], bfr[2];
#pragma unroll
            for (int ms = 0; ms < 4; ms++)
                af[ms] = *(const bf16x8*)(Ab + (size_t)(((wm * 4 + ms) * 2 + s) * 64 + lane) * 16);
#pragma unroll
            for (int ns = 0; ns < 2; ns++)
                bfr[ns] = *(const bf16x8*)(Bb + (size_t)(((wn * 2 + ns) * 2 + s) * 64 + lane) * 16);
#pragma unroll
            for (int ms = 0; ms < 4; ms++)
#pragma unroll
                for (int ns = 0; ns < 2; ns++)
                    acc[ms][ns] = __builtin_amdgcn_mfma_f32_32x32x16_bf16(
                        af[ms], bfr[ns], acc[ms][ns], 0, 0, 0);
        }
    }

    // ---- epilogue: block-local per-row max over all 256 codes ----
    float tmax[2] = {-1e30f, -1e30f};
#pragma unroll
    for (int ms = 0; ms < 4; ms++)
#pragma unroll
        for (int ns = 0; ns < 2; ns++)
#pragma unroll
            for (int r = 0; r < 16; r++)
                tmax[ns] = fmaxf(tmax[ns], acc[ms][ns][r]);
#pragma unroll
    for (int ns = 0; ns < 2; ns++)
        tmax[ns] = fmaxf(tmax[ns], __shfl_xor(tmax[ns], 32));

    __syncthreads();                 // GEMM LDS dead; reuse for rowmax + lcnt
    float* rmx  = (float*)smem;      // [2][256]: [wm][local row]
    int*   lcnt = (int*)(smem + 2048);   // [256] per-row slot counters
    if (lane < 32) {
        rmx[wm * 256 + wn * 64 + 0 * 32 + lane] = tmax[0];
        rmx[wm * 256 + wn * 64 + 1 * 32 + lane] = tmax[1];
    }
    if (tid < 256) lcnt[tid] = 0;
    __syncthreads();

    float thr[2];
#pragma unroll
    for (int ns = 0; ns < 2; ns++) {
        const int lr = wn * 64 + ns * 32 + m;
        thr[ns] = fmaxf(rmx[lr], rmx[256 + lr]) - MARGIN_T;
    }

    // ---- append keepers: LDS-atomic slot reservation + plain stores ----
#pragma unroll
    for (int ms = 0; ms < 4; ms++)
#pragma unroll
        for (int ns = 0; ns < 2; ns++)
#pragma unroll
            for (int r = 0; r < 16; r++) {
                float v = acc[ms][ns][r];
                if (v >= thr[ns]) {
                    const int lr = wn * 64 + ns * 32 + m;
                    int slot = atomicAdd(&lcnt[lr], 1);        // LDS atomic
                    if (slot < SLOTS) {
                        int code = codeBase + wm * 128 + ms * 32
                                 + ((r & 3) + 8 * (r >> 2) + 4 * half);
                        int b = __float_as_int(v);
                        unsigned key = (unsigned)b ^ ((unsigned)(b >> 31) | 0x80000000u);
                        unsigned entry = (key & 0xFFFFF000u) | (unsigned)code;
                        cand2[((size_t)(rowBase + lr) * 16 + cb) * SLOTS + slot] = entry;
                    }
                }
            }

    __syncthreads();
    if (tid < 256) {
        int cf = lcnt[tid];
        cnt8[(size_t)(rowBase + tid) * 16 + cb] =
            (cf > SLOTS) ? (unsigned char)255 : (unsigned char)cf;
        lmax[(size_t)(rowBase + tid) * 16 + cb] = fmaxf(rmx[tid], rmx[256 + tid]);
    }
}

// ---------------------------------------------------------------------------
// K_RESCORE v9: 4 rows per 256-thread block (one WAVE per row), zero
// __syncthreads (all LDS wave-private; intra-wave LDS dependencies are
// ordered by lgkmcnt automatically).
//
// R7 post-mortem: normal path was ~250us at 2.7 waves/CU residency --
// 1-wave workgroups + a long dependent chain (serial 8-deep gather loop,
// RB-batch staging, 4+ barriers). v9: coalesced full-slice gather (all 64
// lanes read cand2[n][0..127] in 2 loads, validity via shfl'd counts),
// ballot-compact, then per-lane survivor chains (identical exact serial
// 256-FMA chain; (dv,k) lexicographic min is visit-order-independent ->
// same argmin). Fallback logic unchanged from R7 (lane-parallel full scan).
// ---------------------------------------------------------------------------
__global__ __launch_bounds__(256) void k_rescore(
    const float* __restrict__ z, const float* __restrict__ w,
    const float* __restrict__ z2, const float* __restrict__ e2,
    const unsigned char* __restrict__ cnt8, const unsigned int* __restrict__ cand2,
    const float* __restrict__ lmax, int* __restrict__ idx_out)
{
#pragma clang fp contract(off)
    const int lane = threadIdx.x & 63;
    const int wv   = threadIdx.x >> 6;          // 0..3
    const int n    = blockIdx.x * 4 + wv;

    __shared__ float4 zst[4][64];               // 4 KB, wave-private slices
    __shared__ int    surv[4][CAP];             // 2 KB, wave-private slices

    zst[wv][lane] = ((const float4*)(z + (size_t)n * D_DIM))[lane];

    // ---- counts + exact global row max ----
    int   c  = 0;
    float lm = -1e30f;
    if (lane < 16) {
        c  = cnt8[(size_t)n * 16 + lane];
        lm = lmax[(size_t)n * 16 + lane];
    }
    float gm = lm;
#pragma unroll
    for (int off = 32; off > 0; off >>= 1)
        gm = fmaxf(gm, __shfl_xor(gm, off));    // wave-uniform exact max

    const bool needfull = __any((c == 255) && (lm >= gm - MARGIN_T));

    float bd = __builtin_inff(); int bk = K_CODES;
    const float z2v = z2[n];

    if (needfull) {
        // ---- lane-parallel exact full scan (wave-uniform branch) ----
        for (int k0 = lane; k0 < K_CODES; k0 += 128) {
            const int kA = k0, kB = k0 + 64;
            const float4* wA = (const float4*)(w + (size_t)kA * D_DIM);
            const float4* wB = (const float4*)(w + (size_t)kB * D_DIM);
            float ta = 0.0f, tb = 0.0f;
#pragma unroll 8
            for (int d4 = 0; d4 < 64; d4++) {
                float4 zv = zst[wv][d4];        // LDS broadcast
                float4 wa = wA[d4];
                float4 wb2 = wB[d4];
                ta = __builtin_fmaf(zv.x, wa.x, ta);
                tb = __builtin_fmaf(zv.x, wb2.x, tb);
                ta = __builtin_fmaf(zv.y, wa.y, ta);
                tb = __builtin_fmaf(zv.y, wb2.y, tb);
                ta = __builtin_fmaf(zv.z, wa.z, ta);
                tb = __builtin_fmaf(zv.z, wb2.z, tb);
                ta = __builtin_fmaf(zv.w, wa.w, ta);
                tb = __builtin_fmaf(zv.w, wb2.w, tb);
            }
            float uA = z2v - 2.0f * ta;
            float dA = uA + e2[kA];
            float uB = z2v - 2.0f * tb;
            float dB = uB + e2[kB];
            if (dA < bd || (dA == bd && kA < bk)) { bd = dA; bk = kA; }
            if (dB < bd || (dB == bd && kB < bk)) { bd = dB; bk = kB; }
        }
    } else {
        // ---- coalesced full-slice gather + filter ----
        // entry positions p = lane and p = 64+lane; cb = p>>3, j = p&7;
        // valid iff j < cl(cb). Slots beyond cl are stale -> discarded.
        const unsigned e0 = cand2[(size_t)n * 128 + lane];
        const unsigned e1 = cand2[(size_t)n * 128 + 64 + lane];
        const int craw0 = __shfl(c, lane >> 3);           // cb0 = lane>>3 (0..7)
        const int craw1 = __shfl(c, 8 + (lane >> 3));     // cb1 = 8+(lane>>3)
        const int cl0 = (craw0 == 255) ? SLOTS : craw0;
        const int cl1 = (craw1 == 255) ? SLOTS : craw1;
        const float thrF = gm - MARGIN_T - 1e-4f;         // key-truncation slack

        auto keyf = [](unsigned e) -> float {
            unsigned ky = e & 0xFFFFF000u;
            int b = (ky & 0x80000000u) ? (int)(ky ^ 0x80000000u) : (int)~ky;
            return __int_as_float(b);
        };
        const bool keep0 = ((lane & 7) < cl0) && (keyf(e0) >= thrF);
        const bool keep1 = ((lane & 7) < cl1) && (keyf(e1) >= thrF);

        unsigned long long bal0 = __ballot(keep0);
        unsigned long long bal1 = __ballot(keep1);
        const unsigned long long below = (1ull << lane) - 1ull;
        const int n0 = (int)__popcll(bal0);
        if (keep0) surv[wv][(int)__popcll(bal0 & below)] = (int)(e0 & 0xFFFu);
        if (keep1) surv[wv][n0 + (int)__popcll(bal1 & below)] = (int)(e1 & 0xFFFu);
        const int nt = n0 + (int)__popcll(bal1);          // >= 1 (gm entry stored)

        // ---- per-lane exact survivor chains (nt typically 1-3) ----
        for (int s = lane; s < nt; s += 64) {
            int k = surv[wv][s];
            if ((unsigned)k >= (unsigned)K_CODES) k = 0;  // defensive
            const float4* wp = (const float4*)(w + (size_t)k * D_DIM);
            float tacc = 0.0f;
#pragma unroll 8
            for (int d4 = 0; d4 < 64; d4++) {
                float4 wvv = wp[d4];
                float4 zv  = zst[wv][d4];
                tacc = __builtin_fmaf(zv.x, wvv.x, tacc);
                tacc = __builtin_fmaf(zv.y, wvv.y, tacc);
                tacc = __builtin_fmaf(zv.z, wvv.z, tacc);
                tacc = __builtin_fmaf(zv.w, wvv.w, tacc);
            }
            float u  = z2v - 2.0f * tacc;   // 2*tacc exact -> single rounding
            float dv = u + e2[k];
            if (dv < bd || (dv == bd && k < bk)) { bd = dv; bk = k; }
        }
    }

#pragma unroll
    for (int off = 1; off < 64; off <<= 1) {
        float od = __shfl_xor(bd, off);
        int   ok = __shfl_xor(bk, off);
        if (od < bd || (od == bd && ok < bk)) { bd = od; bk = ok; }
    }
    if (lane == 0) idx_out[n] = (bk < K_CODES) ? bk : 0;
}

// ---------------------------------------------------------------------------
// K3: gather z_q, STE output, loss partials, counts + dw atomics.
// ---------------------------------------------------------------------------
__global__ void k3_scatter(const float* __restrict__ z, const float* __restrict__ w,
                           const int* __restrict__ idx_in,
                           float* __restrict__ counts, float* __restrict__ lossp,
                           float* __restrict__ dw, float* __restrict__ out_zq,
                           float* __restrict__ out_idx)
{
#pragma clang fp contract(off)
    const int n = blockIdx.x;
    const int t = threadIdx.x;
    int idx = idx_in[n];
    if (idx < 0) idx = 0;
    if (idx >= K_CODES) idx = K_CODES - 1;     // defensive clamp (no fault)
    if (t == 0) {
        out_idx[n] = (float)idx;
        atomicAdd(&counts[idx], 1.0f);
    }
    float zv = z[(size_t)n * D_DIM + t];
    float wq = w[(size_t)idx * D_DIM + t];
    out_zq[(size_t)n * D_DIM + t] = zv + (wq - zv);
    float df = zv - wq;
    float sq = df * df;
    atomicAdd(&dw[(size_t)idx * D_DIM + t], zv);

    __shared__ float red[256];
    red[t] = sq; __syncthreads();
    for (int s = 128; s > 0; s >>= 1) {
        if (t < s) red[t] += red[t + s];
        __syncthreads();
    }
    if (t == 0) lossp[n] = red[0];
}

// ---------------------------------------------------------------------------
// K4: vq_loss finalize + new_cs (Laplace smoothing). Single block, 1024 thr.
// ---------------------------------------------------------------------------
__global__ void k4_cs(const float* __restrict__ lossp, const float* __restrict__ counts,
                      const float* __restrict__ cs_in, float* __restrict__ out_loss,
                      float* __restrict__ out_cs)
{
#pragma clang fp contract(off)
    const int t = threadIdx.x;
    __shared__ float red[1024];
    __shared__ float pre[K_CODES];

    float s = 0.0f;
    for (int i = t; i < N_ROWS; i += 1024) s += lossp[i];
    red[t] = s; __syncthreads();
    for (int st = 512; st > 0; st >>= 1) {
        if (t < st) red[t] += red[t + st];
        __syncthreads();
    }
    if (t == 0) out_loss[0] = 0.25f * (red[0] / 8388608.0f);
    __syncthreads();

    const float DEC = 0.99f;
    const float OMD = (float)(1.0 - 0.99);
    float mine[4];
#pragma unroll
    for (int q = 0; q < 4; q++) {
        int k = t + q * 1024;
        float t1 = DEC * cs_in[k];
        float t2 = OMD * counts[k];
        float p = t1 + t2;
        pre[k] = p; mine[q] = p;
    }
    float psum = (mine[0] + mine[1]) + (mine[2] + mine[3]);
    red[t] = psum; __syncthreads();
    for (int st = 512; st > 0; st >>= 1) {
        if (t < st) red[t] += red[t + st];
        __syncthreads();
    }
    float nsum = red[0];
    const float KEPS = (float)(4096.0 * 1e-5);
    float denom = nsum + KEPS;
#pragma unroll
    for (int q = 0; q < 4; q++) {
        int k = t + q * 1024;
        float v = ((pre[k] + 1e-5f) / denom) * nsum;
        out_cs[k] = v;
    }
}

// ---------------------------------------------------------------------------
// K5: new_ema_w = 0.99*ema_w + 0.01*dw ; new_weight = new_ema_w / new_cs[k]
// ---------------------------------------------------------------------------
__global__ void k5_emaw(const float* __restrict__ ema_w, const float* __restrict__ dw,
                        const float* __restrict__ newcs, float* __restrict__ out_w,
                        float* __restrict__ out_emaw)
{
#pragma clang fp contract(off)
    const int i = blockIdx.x * 256 + threadIdx.x;
    const int k = i >> 8;
    const float OMD = (float)(1.0 - 0.99);
    float t1 = 0.99f * ema_w[i];
    float t2 = OMD * dw[i];
    float ne = t1 + t2;
    out_emaw[i] = ne;
    out_w[i] = ne / newcs[k];
}

extern "C" void kernel_launch(void* const* d_in, const int* in_sizes, int n_in,
                              void* d_out, int out_size, void* d_ws, size_t ws_size,
                              hipStream_t stream)
{
    const float* z    = (const float*)d_in[0];
    const float* w    = (const float*)d_in[1];
    const float* cs   = (const float*)d_in[2];
    const float* emaw = (const float*)d_in[3];

    float* out      = (float*)d_out;
    float* out_zq   = out;                    // 8388608
    float* out_idx  = out + 8388608;          // 32768
    float* out_loss = out + 8421376;          // 1
    float* out_w    = out + 8421377;          // 1048576
    float* out_cs   = out + 9469953;          // 4096
    float* out_emaw = out + 9474049;          // 1048576

    char* ws = (char*)d_ws;
    float*          counts  = (float*)(ws + WS_COUNTS);
    float*          lossp   = (float*)(ws + WS_LOSSP);
    int*            idx_int = (int*)  (ws + WS_IDX);
    float*          z2      = (float*)(ws + WS_Z2);
    float*          e2      = (float*)(ws + WS_E2);
    float*          dw      = (float*)(ws + WS_DW);

    // big scratch lives in d_out (consumed by rescore before k3/k4/k5 rewrite it)
    char* ob = (char*)d_out;
    unsigned short* zb    = (unsigned short*)(ob + DO_ZB);
    unsigned short* wb    = (unsigned short*)(ob + DO_WB);
    unsigned int*   cand2 = (unsigned int*)  (ob + DO_CAND);
    unsigned char*  cnt8  = (unsigned char*) (ob + DO_CNT8);
    float*          lmx   = (float*)         (ob + DO_LMAX);

    hipMemsetAsync(counts, 0, K_CODES * sizeof(float), stream);
    hipMemsetAsync(dw, 0, (size_t)K_CODES * D_DIM * sizeof(float), stream);

    k1_norms<<<(N_ROWS + K_CODES) / 256, 256, 0, stream>>>(z, w, z2, e2);

    // 4608 waves: (36864 rows / 64 rows-per-wave) * 8 kk-panels; 4 waves/block
    kconv<<<1152, 256, 0, stream>>>(z, w, zb, wb);

    dim3 g2(16, 128);   // x = code-block, y = row-block (swizzled in-kernel)
    k2_scan<<<g2, 512, 0, stream>>>(zb, wb, cnt8, cand2, lmx);

    // 4 rows per 256-thread block (one wave per row)
    k_rescore<<<N_ROWS / 4, 256, 0, stream>>>(z, w, z2, e2, cnt8, cand2, lmx, idx_int);

    k3_scatter<<<N_ROWS, 256, 0, stream>>>(z, w, idx_int, counts, lossp,
                                           dw, out_zq, out_idx);

    k4_cs<<<1, 1024, 0, stream>>>(lossp, counts, cs, out_loss, out_cs);

    k5_emaw<<<K_CODES, 256, 0, stream>>>(emaw, dw, out_cs, out_w, out_emaw);
}

// Round 9
// 372.071 us; speedup vs baseline: 49.3419x; 1.5341x over previous
//
#include <hip/hip_runtime.h>
#include <hip/hip_bf16.h>

#define N_ROWS 32768
#define K_CODES 4096
#define D_DIM 256
#define CAP 128
#define MARGIN_T 1e-3f
#define SLOTS 8

// ---- d_ws layout (bytes) -- total 4,882,432 ----
#define WS_COUNTS    0          // float[4096]
#define WS_LOSSP     16384      // float[32768]
#define WS_IDX       147456     // int[32768]
#define WS_Z2        278528     // float[32768]
#define WS_E2        409600     // float[4096]
#define WS_DW        688128     // float[1048576] -> ends 4882432

// ---- d_out scratch (all regions consumed by rescore before k3/k4/k5 rewrite) ----
#define DO_ZB        0          // ushort[32768*256] = 16 MB (panel layout)
#define DO_WB        16777216   // ushort[4096*256]  =  2 MB (panel layout)
#define DO_CAND      18874368   // uint[32768][16][8] = 16 MB -> ends 35651584
#define DO_CNT8      35651584   // uchar[32768][16]  = 512 KB -> ends 36175872
#define DO_LMAX      36175872   // float[32768][16]  =   2 MB -> ends 38273024 (< 42.09 MB)

typedef __attribute__((ext_vector_type(8)))  short bf16x8;
typedef __attribute__((ext_vector_type(16))) float f32x16;
typedef __attribute__((ext_vector_type(8)))  unsigned short us8;

// ---------------------------------------------------------------------------
// K1: z2/e2 with numpy's exact pairwise structure (proven in R1)
// ---------------------------------------------------------------------------
__global__ void k1_norms(const float* __restrict__ z, const float* __restrict__ w,
                         float* __restrict__ z2, float* __restrict__ e2)
{
#pragma clang fp contract(off)
    int gid = blockIdx.x * blockDim.x + threadIdx.x;
    const float* row;
    float* outp;
    if (gid < N_ROWS) { row = z + (size_t)gid * D_DIM; outp = z2 + gid; }
    else if (gid < N_ROWS + K_CODES) { row = w + (size_t)(gid - N_ROWS) * D_DIM; outp = e2 + (gid - N_ROWS); }
    else return;

    float total = 0.0f;
    for (int half = 0; half < 2; half++) {
        const float* x = row + half * 128;
        float r[8];
#pragma unroll
        for (int j = 0; j < 8; j++) { float v = x[j]; r[j] = v * v; }
        for (int i = 8; i < 128; i += 8) {
#pragma unroll
            for (int j = 0; j < 8; j++) { float v = x[i + j]; r[j] += v * v; }
        }
        float s = ((r[0] + r[1]) + (r[2] + r[3])) + ((r[4] + r[5]) + (r[6] + r[7]));
        if (half == 0) total = s; else total = total + s;
    }
    *outp = total;
}

// ---------------------------------------------------------------------------
// KCONV v2 (proven R4): fp32 -> bf16 (RNE) in "LDS-image" PANEL layout so
// k2's staging is a straight contiguous copy. Bit-identical LDS bytes vs R3.
// ---------------------------------------------------------------------------
__device__ inline unsigned short f2b(float f) {
    __hip_bfloat16 h = __float2bfloat16(f);
    return *(unsigned short*)&h;
}

__global__ void kconv(const float* __restrict__ z, const float* __restrict__ w,
                      unsigned short* __restrict__ zb, unsigned short* __restrict__ wb)
{
    const int lane  = threadIdx.x & 63;
    const int gwave = blockIdx.x * 4 + (threadIdx.x >> 6);   // 0..4607
    const int kk    = gwave & 7;
    const int row   = (gwave >> 3) * 64 + lane;              // 0..36863
    const float* src;
    unsigned short* panel;
    int g;
    if (row < N_ROWS) {
        src   = z + (size_t)row * D_DIM;
        panel = zb + ((size_t)((row >> 8) * 8 + kk) << 13);
        g     = (row >> 5) & 7;
    } else {
        int c = row - N_ROWS;
        src   = w + (size_t)c * D_DIM;
        panel = wb + ((size_t)((c >> 8) * 8 + kk) << 13);
        g     = (c >> 5) & 7;
    }
    const int r31 = row & 31;
    const float* s0 = src + kk * 32;
#pragma unroll
    for (int s = 0; s < 2; s++)
#pragma unroll
        for (int h = 0; h < 2; h++) {
            float4 a = *(const float4*)(s0 + s * 16 + h * 8);
            float4 b = *(const float4*)(s0 + s * 16 + h * 8 + 4);
            us8 o;
            o[0] = f2b(a.x); o[1] = f2b(a.y); o[2] = f2b(a.z); o[3] = f2b(a.w);
            o[4] = f2b(b.x); o[5] = f2b(b.y); o[6] = f2b(b.z); o[7] = f2b(b.w);
            *(us8*)(panel + (((g * 2 + s) * 64 + h * 32 + r31) << 3)) = o;
        }
}

// ---------------------------------------------------------------------------
// async global->LDS, 16B per lane. LDS dest = wave-uniform base + lane*16.
// ---------------------------------------------------------------------------
__device__ inline void gload16(const void* g, void* l)
{
    __builtin_amdgcn_global_load_lds(
        (const __attribute__((address_space(1))) unsigned int*)g,
        (__attribute__((address_space(3))) unsigned int*)l,
        16, 0, 0);
}

// ---------------------------------------------------------------------------
// K2 v5.1 (unchanged from R6/R7/R8): 256x256-tile bf16 MFMA GEMM, atomic-free
// append (LDS-atomic slot reservation, per-(row,cb) 8-slot regions, plain
// stores), exact fp32 block-local row max to lmax.
// ---------------------------------------------------------------------------
__global__ __launch_bounds__(512, 2) void k2_scan(
    const unsigned short* __restrict__ zb, const unsigned short* __restrict__ wb,
    unsigned char* __restrict__ cnt8, unsigned int* __restrict__ cand2,
    float* __restrict__ lmax)
{
    __shared__ char smem[65536];
    const int tid  = threadIdx.x;
    const int lane = tid & 63;
    const int wid  = tid >> 6;     // 0..7
    const int wm   = wid >> 2;     // code-wave 0..1
    const int wn   = wid & 3;      // row-wave 0..3
    const int m    = lane & 31;
    const int half = lane >> 5;

    // bijective XCD swizzle: XCD(r_hw) == o/256 (proven R3/R4: FETCH 17MB)
    const int r_hw = blockIdx.y * 16 + blockIdx.x;
    const int o    = (r_hw & 7) * 256 + (r_hw >> 3);
    const int cb   = o & 15;       // code-block 0..15
    const int rb   = o >> 4;       // row-block  0..127
    const int rowBase  = rb * 256;
    const int codeBase = cb * 256;

    // linear panel copy: A panel (wb) and B panel (zb) for window kk.
    auto stage = [&](int kk, int buf) {
        char* Ab = smem + buf * 32768;
        char* Bb = Ab + 16384;
        const unsigned short* Ap = wb + ((size_t)(cb * 8 + kk) << 13);
        const unsigned short* Bp = zb + ((size_t)(rb * 8 + kk) << 13);
#pragma unroll
        for (int i = 0; i < 2; i++) {
            gload16(Ap + (size_t)((i * 512 + tid) << 3), Ab + (size_t)(i * 512 + tid) * 16);
            gload16(Bp + (size_t)((i * 512 + tid) << 3), Bb + (size_t)(i * 512 + tid) * 16);
        }
    };

    f32x16 acc[4][2];
    {
        f32x16 zz = {};
#pragma unroll
        for (int ms = 0; ms < 4; ms++)
#pragma unroll
            for (int ns = 0; ns < 2; ns++) acc[ms][ns] = zz;
    }

    stage(0, 0);

    for (int kk = 0; kk < 8; kk++) {
        const int buf = kk & 1;
        __syncthreads();                       // drains vmcnt -> buf ready
        if (kk + 1 < 8) stage(kk + 1, buf ^ 1);
        const char* Ab = smem + buf * 32768;
        const char* Bb = Ab + 16384;
#pragma unroll
        for (int s = 0; s < 2; s++) {
            bf16x8 af[4], bfr[2];
#pragma unroll
            for (int ms = 0; ms < 4; ms++)
                af[ms] = *(const bf16x8*)(Ab + (size_t)(((wm * 4 + ms) * 2 + s) * 64 + lane) * 16);
#pragma unroll
            for (int ns = 0; ns < 2; ns++)
                bfr[ns] = *(const bf16x8*)(Bb + (size_t)(((wn * 2 + ns) * 2 + s) * 64 + lane) * 16);
#pragma unroll
            for (int ms = 0; ms < 4; ms++)
#pragma unroll
                for (int ns = 0; ns < 2; ns++)
                    acc[ms][ns] = __builtin_amdgcn_mfma_f32_32x32x16_bf16(
                        af[ms], bfr[ns], acc[ms][ns], 0, 0, 0);
        }
    }

    // ---- epilogue: block-local per-row max over all 256 codes ----
    float tmax[2] = {-1e30f, -1e30f};
#pragma unroll
    for (int ms = 0; ms < 4; ms++)
#pragma unroll
        for (int ns = 0; ns < 2; ns++)
#pragma unroll
            for (int r = 0; r < 16; r++)
                tmax[ns] = fmaxf(tmax[ns], acc[ms][ns][r]);
#pragma unroll
    for (int ns = 0; ns < 2; ns++)
        tmax[ns] = fmaxf(tmax[ns], __shfl_xor(tmax[ns], 32));

    __syncthreads();                 // GEMM LDS dead; reuse for rowmax + lcnt
    float* rmx  = (float*)smem;      // [2][256]: [wm][local row]
    int*   lcnt = (int*)(smem + 2048);   // [256] per-row slot counters
    if (lane < 32) {
        rmx[wm * 256 + wn * 64 + 0 * 32 + lane] = tmax[0];
        rmx[wm * 256 + wn * 64 + 1 * 32 + lane] = tmax[1];
    }
    if (tid < 256) lcnt[tid] = 0;
    __syncthreads();

    float thr[2];
#pragma unroll
    for (int ns = 0; ns < 2; ns++) {
        const int lr = wn * 64 + ns * 32 + m;
        thr[ns] = fmaxf(rmx[lr], rmx[256 + lr]) - MARGIN_T;
    }

    // ---- append keepers: LDS-atomic slot reservation + plain stores ----
#pragma unroll
    for (int ms = 0; ms < 4; ms++)
#pragma unroll
        for (int ns = 0; ns < 2; ns++)
#pragma unroll
            for (int r = 0; r < 16; r++) {
                float v = acc[ms][ns][r];
                if (v >= thr[ns]) {
                    const int lr = wn * 64 + ns * 32 + m;
                    int slot = atomicAdd(&lcnt[lr], 1);        // LDS atomic
                    if (slot < SLOTS) {
                        int code = codeBase + wm * 128 + ms * 32
                                 + ((r & 3) + 8 * (r >> 2) + 4 * half);
                        int b = __float_as_int(v);
                        unsigned key = (unsigned)b ^ ((unsigned)(b >> 31) | 0x80000000u);
                        unsigned entry = (key & 0xFFFFF000u) | (unsigned)code;
                        cand2[((size_t)(rowBase + lr) * 16 + cb) * SLOTS + slot] = entry;
                    }
                }
            }

    __syncthreads();
    if (tid < 256) {
        int cf = lcnt[tid];
        cnt8[(size_t)(rowBase + tid) * 16 + cb] =
            (cf > SLOTS) ? (unsigned char)255 : (unsigned char)cf;
        lmax[(size_t)(rowBase + tid) * 16 + cb] = fmaxf(rmx[tid], rmx[256 + tid]);
    }
}

// ---------------------------------------------------------------------------
// K_RESCORE v10: 4 rows per 256-thread block (one WAVE per row), zero
// __syncthreads (all LDS wave-private).
//
// R8 post-mortem: the FULL-4096 fallback scan was ~270us of the kernel in
// R7/R8 -- scatter-bound (each lane owns a w row, 16B/lane/step = 64-way
// scatter, ~4MB L2 traffic per fallback row ~ 100us). v10 REPLACES the full
// scan with per-block recovery: a qualifying overflow block (cnt8==255 AND
// lmax >= gm-MARGIN) gets its 256 codes exact-rescored (4 codes/lane, 4
// interleaved exact serial chains; 256KB scattered ~ 10us, 16x less).
// Safety: if the true argmin's block didn't overflow, its entry is in cand2
// and passes the filter; if it overflowed, lmax >= score(argmin) >=
// gm-MARGIN so the block qualifies and is fully rescored. Overflow blocks
// with lmax < gm-MARGIN contain no qualifying codes (R6-proven). Chains are
// the identical ascending-d single-accumulator recurrence -> bit-identical
// distances; duplicates are harmless under the (dv,k) lexicographic min.
// Normal gather/filter/survivor path unchanged from R8.
// ---------------------------------------------------------------------------
__global__ __launch_bounds__(256) void k_rescore(
    const float* __restrict__ z, const float* __restrict__ w,
    const float* __restrict__ z2, const float* __restrict__ e2,
    const unsigned char* __restrict__ cnt8, const unsigned int* __restrict__ cand2,
    const float* __restrict__ lmax, int* __restrict__ idx_out)
{
#pragma clang fp contract(off)
    const int lane = threadIdx.x & 63;
    const int wv   = threadIdx.x >> 6;          // 0..3
    const int n    = blockIdx.x * 4 + wv;

    __shared__ float4 zst[4][64];               // 4 KB, wave-private slices
    __shared__ int    surv[4][CAP];             // 2 KB, wave-private slices

    zst[wv][lane] = ((const float4*)(z + (size_t)n * D_DIM))[lane];

    // ---- counts + exact global row max ----
    int   c  = 0;
    float lm = -1e30f;
    if (lane < 16) {
        c  = cnt8[(size_t)n * 16 + lane];
        lm = lmax[(size_t)n * 16 + lane];
    }
    float gm = lm;
#pragma unroll
    for (int off = 32; off > 0; off >>= 1)
        gm = fmaxf(gm, __shfl_xor(gm, off));    // wave-uniform exact max

    // mask of qualifying overflow blocks (bits 0..15); wave-uniform
    unsigned long long obal =
        __ballot((lane < 16) && (c == 255) && (lm >= gm - MARGIN_T));

    float bd = __builtin_inff(); int bk = K_CODES;
    const float z2v = z2[n];

    // ---- coalesced full-slice gather + filter (always) ----
    {
        const unsigned e0 = cand2[(size_t)n * 128 + lane];
        const unsigned e1 = cand2[(size_t)n * 128 + 64 + lane];
        const int craw0 = __shfl(c, lane >> 3);           // cb0 = lane>>3 (0..7)
        const int craw1 = __shfl(c, 8 + (lane >> 3));     // cb1 = 8+(lane>>3)
        const int cl0 = (craw0 == 255) ? SLOTS : craw0;
        const int cl1 = (craw1 == 255) ? SLOTS : craw1;
        const float thrF = gm - MARGIN_T - 1e-4f;         // key-truncation slack

        auto keyf = [](unsigned e) -> float {
            unsigned ky = e & 0xFFFFF000u;
            int b = (ky & 0x80000000u) ? (int)(ky ^ 0x80000000u) : (int)~ky;
            return __int_as_float(b);
        };
        const bool keep0 = ((lane & 7) < cl0) && (keyf(e0) >= thrF);
        const bool keep1 = ((lane & 7) < cl1) && (keyf(e1) >= thrF);

        unsigned long long bal0 = __ballot(keep0);
        unsigned long long bal1 = __ballot(keep1);
        const unsigned long long below = (1ull << lane) - 1ull;
        const int n0 = (int)__popcll(bal0);
        if (keep0) surv[wv][(int)__popcll(bal0 & below)] = (int)(e0 & 0xFFFu);
        if (keep1) surv[wv][n0 + (int)__popcll(bal1 & below)] = (int)(e1 & 0xFFFu);
        const int nt = n0 + (int)__popcll(bal1);

        // ---- per-lane exact survivor chains (nt typically 1-3) ----
        for (int s = lane; s < nt; s += 64) {
            int k = surv[wv][s];
            if ((unsigned)k >= (unsigned)K_CODES) k = 0;  // defensive
            const float4* wp = (const float4*)(w + (size_t)k * D_DIM);
            float tacc = 0.0f;
#pragma unroll 8
            for (int d4 = 0; d4 < 64; d4++) {
                float4 wvv = wp[d4];
                float4 zv  = zst[wv][d4];
                tacc = __builtin_fmaf(zv.x, wvv.x, tacc);
                tacc = __builtin_fmaf(zv.y, wvv.y, tacc);
                tacc = __builtin_fmaf(zv.z, wvv.z, tacc);
                tacc = __builtin_fmaf(zv.w, wvv.w, tacc);
            }
            float u  = z2v - 2.0f * tacc;   // 2*tacc exact -> single rounding
            float dv = u + e2[k];
            if (dv < bd || (dv == bd && k < bk)) { bd = dv; bk = k; }
        }
    }

    // ---- per-block exact recovery of qualifying overflow blocks (rare) ----
    while (obal) {
        const int cbq = (int)(__ffsll((long long)obal) - 1);
        obal &= obal - 1ull;
        const int k0 = cbq * 256 + lane;      // lane's 4 codes: +0,+64,+128,+192
        const float4* w0 = (const float4*)(w + (size_t)(k0      ) * D_DIM);
        const float4* w1 = (const float4*)(w + (size_t)(k0 +  64) * D_DIM);
        const float4* w2 = (const float4*)(w + (size_t)(k0 + 128) * D_DIM);
        const float4* w3 = (const float4*)(w + (size_t)(k0 + 192) * D_DIM);
        float t0 = 0.0f, t1 = 0.0f, t2 = 0.0f, t3 = 0.0f;
#pragma unroll 8
        for (int d4 = 0; d4 < 64; d4++) {
            float4 zv = zst[wv][d4];          // LDS broadcast
            float4 a0 = w0[d4];
            float4 a1 = w1[d4];
            float4 a2 = w2[d4];
            float4 a3 = w3[d4];
            t0 = __builtin_fmaf(zv.x, a0.x, t0);
            t1 = __builtin_fmaf(zv.x, a1.x, t1);
            t2 = __builtin_fmaf(zv.x, a2.x, t2);
            t3 = __builtin_fmaf(zv.x, a3.x, t3);
            t0 = __builtin_fmaf(zv.y, a0.y, t0);
            t1 = __builtin_fmaf(zv.y, a1.y, t1);
            t2 = __builtin_fmaf(zv.y, a2.y, t2);
            t3 = __builtin_fmaf(zv.y, a3.y, t3);
            t0 = __builtin_fmaf(zv.z, a0.z, t0);
            t1 = __builtin_fmaf(zv.z, a1.z, t1);
            t2 = __builtin_fmaf(zv.z, a2.z, t2);
            t3 = __builtin_fmaf(zv.z, a3.z, t3);
            t0 = __builtin_fmaf(zv.w, a0.w, t0);
            t1 = __builtin_fmaf(zv.w, a1.w, t1);
            t2 = __builtin_fmaf(zv.w, a2.w, t2);
            t3 = __builtin_fmaf(zv.w, a3.w, t3);
        }
        float d0 = (z2v - 2.0f * t0) + e2[k0];
        float d1 = (z2v - 2.0f * t1) + e2[k0 + 64];
        float d2 = (z2v - 2.0f * t2) + e2[k0 + 128];
        float d3 = (z2v - 2.0f * t3) + e2[k0 + 192];
        if (d0 < bd || (d0 == bd && k0       < bk)) { bd = d0; bk = k0; }
        if (d1 < bd || (d1 == bd && k0 +  64 < bk)) { bd = d1; bk = k0 + 64; }
        if (d2 < bd || (d2 == bd && k0 + 128 < bk)) { bd = d2; bk = k0 + 128; }
        if (d3 < bd || (d3 == bd && k0 + 192 < bk)) { bd = d3; bk = k0 + 192; }
    }

#pragma unroll
    for (int off = 1; off < 64; off <<= 1) {
        float od = __shfl_xor(bd, off);
        int   ok = __shfl_xor(bk, off);
        if (od < bd || (od == bd && ok < bk)) { bd = od; bk = ok; }
    }
    if (lane == 0) idx_out[n] = (bk < K_CODES) ? bk : 0;
}

// ---------------------------------------------------------------------------
// K3: gather z_q, STE output, loss partials, counts + dw atomics.
// ---------------------------------------------------------------------------
__global__ void k3_scatter(const float* __restrict__ z, const float* __restrict__ w,
                           const int* __restrict__ idx_in,
                           float* __restrict__ counts, float* __restrict__ lossp,
                           float* __restrict__ dw, float* __restrict__ out_zq,
                           float* __restrict__ out_idx)
{
#pragma clang fp contract(off)
    const int n = blockIdx.x;
    const int t = threadIdx.x;
    int idx = idx_in[n];
    if (idx < 0) idx = 0;
    if (idx >= K_CODES) idx = K_CODES - 1;     // defensive clamp (no fault)
    if (t == 0) {
        out_idx[n] = (float)idx;
        atomicAdd(&counts[idx], 1.0f);
    }
    float zv = z[(size_t)n * D_DIM + t];
    float wq = w[(size_t)idx * D_DIM + t];
    out_zq[(size_t)n * D_DIM + t] = zv + (wq - zv);
    float df = zv - wq;
    float sq = df * df;
    atomicAdd(&dw[(size_t)idx * D_DIM + t], zv);

    __shared__ float red[256];
    red[t] = sq; __syncthreads();
    for (int s = 128; s > 0; s >>= 1) {
        if (t < s) red[t] += red[t + s];
        __syncthreads();
    }
    if (t == 0) lossp[n] = red[0];
}

// ---------------------------------------------------------------------------
// K4: vq_loss finalize + new_cs (Laplace smoothing). Single block, 1024 thr.
// ---------------------------------------------------------------------------
__global__ void k4_cs(const float* __restrict__ lossp, const float* __restrict__ counts,
                      const float* __restrict__ cs_in, float* __restrict__ out_loss,
                      float* __restrict__ out_cs)
{
#pragma clang fp contract(off)
    const int t = threadIdx.x;
    __shared__ float red[1024];
    __shared__ float pre[K_CODES];

    float s = 0.0f;
    for (int i = t; i < N_ROWS; i += 1024) s += lossp[i];
    red[t] = s; __syncthreads();
    for (int st = 512; st > 0; st >>= 1) {
        if (t < st) red[t] += red[t + st];
        __syncthreads();
    }
    if (t == 0) out_loss[0] = 0.25f * (red[0] / 8388608.0f);
    __syncthreads();

    const float DEC = 0.99f;
    const float OMD = (float)(1.0 - 0.99);
    float mine[4];
#pragma unroll
    for (int q = 0; q < 4; q++) {
        int k = t + q * 1024;
        float t1 = DEC * cs_in[k];
        float t2 = OMD * counts[k];
        float p = t1 + t2;
        pre[k] = p; mine[q] = p;
    }
    float psum = (mine[0] + mine[1]) + (mine[2] + mine[3]);
    red[t] = psum; __syncthreads();
    for (int st = 512; st > 0; st >>= 1) {
        if (t < st) red[t] += red[t + st];
        __syncthreads();
    }
    float nsum = red[0];
    const float KEPS = (float)(4096.0 * 1e-5);
    float denom = nsum + KEPS;
#pragma unroll
    for (int q = 0; q < 4; q++) {
        int k = t + q * 1024;
        float v = ((pre[k] + 1e-5f) / denom) * nsum;
        out_cs[k] = v;
    }
}

// ---------------------------------------------------------------------------
// K5: new_ema_w = 0.99*ema_w + 0.01*dw ; new_weight = new_ema_w / new_cs[k]
// ---------------------------------------------------------------------------
__global__ void k5_emaw(const float* __restrict__ ema_w, const float* __restrict__ dw,
                        const float* __restrict__ newcs, float* __restrict__ out_w,
                        float* __restrict__ out_emaw)
{
#pragma clang fp contract(off)
    const int i = blockIdx.x * 256 + threadIdx.x;
    const int k = i >> 8;
    const float OMD = (float)(1.0 - 0.99);
    float t1 = 0.99f * ema_w[i];
    float t2 = OMD * dw[i];
    float ne = t1 + t2;
    out_emaw[i] = ne;
    out_w[i] = ne / newcs[k];
}

extern "C" void kernel_launch(void* const* d_in, const int* in_sizes, int n_in,
                              void* d_out, int out_size, void* d_ws, size_t ws_size,
                              hipStream_t stream)
{
    const float* z    = (const float*)d_in[0];
    const float* w    = (const float*)d_in[1];
    const float* cs   = (const float*)d_in[2];
    const float* emaw = (const float*)d_in[3];

    float* out      = (float*)d_out;
    float* out_zq   = out;                    // 8388608
    float* out_idx  = out + 8388608;          // 32768
    float* out_loss = out + 8421376;          // 1
    float* out_w    = out + 8421377;          // 1048576
    float* out_cs   = out + 9469953;          // 4096
    float* out_emaw = out + 9474049;          // 1048576

    char* ws = (char*)d_ws;
    float*          counts  = (float*)(ws + WS_COUNTS);
    float*          lossp   = (float*)(ws + WS_LOSSP);
    int*            idx_int = (int*)  (ws + WS_IDX);
    float*          z2      = (float*)(ws + WS_Z2);
    float*          e2      = (float*)(ws + WS_E2);
    float*          dw      = (float*)(ws + WS_DW);

    // big scratch lives in d_out (consumed by rescore before k3/k4/k5 rewrite it)
    char* ob = (char*)d_out;
    unsigned short* zb    = (unsigned short*)(ob + DO_ZB);
    unsigned short* wb    = (unsigned short*)(ob + DO_WB);
    unsigned int*   cand2 = (unsigned int*)  (ob + DO_CAND);
    unsigned char*  cnt8  = (unsigned char*) (ob + DO_CNT8);
    float*          lmx   = (float*)         (ob + DO_LMAX);

    hipMemsetAsync(counts, 0, K_CODES * sizeof(float), stream);
    hipMemsetAsync(dw, 0, (size_t)K_CODES * D_DIM * sizeof(float), stream);

    k1_norms<<<(N_ROWS + K_CODES) / 256, 256, 0, stream>>>(z, w, z2, e2);

    // 4608 waves: (36864 rows / 64 rows-per-wave) * 8 kk-panels; 4 waves/block
    kconv<<<1152, 256, 0, stream>>>(z, w, zb, wb);

    dim3 g2(16, 128);   // x = code-block, y = row-block (swizzled in-kernel)
    k2_scan<<<g2, 512, 0, stream>>>(zb, wb, cnt8, cand2, lmx);

    // 4 rows per 256-thread block (one wave per row)
    k_rescore<<<N_ROWS / 4, 256, 0, stream>>>(z, w, z2, e2, cnt8, cand2, lmx, idx_int);

    k3_scatter<<<N_ROWS, 256, 0, stream>>>(z, w, idx_int, counts, lossp,
                                           dw, out_zq, out_idx);

    k4_cs<<<1, 1024, 0, stream>>>(lossp, counts, cs, out_loss, out_cs);

    k5_emaw<<<K_CODES, 256, 0, stream>>>(emaw, dw, out_cs, out_w, out_emaw);
}